// Round 9
// baseline (431.865 us; speedup 1.0000x reference)
//
#include <hip/hip_runtime.h>
#include <hip/hip_bf16.h>

#define NNODE 10000
#define NEDGE 160000
#define HIDD  256
#define ED    128
#define CAT   640

typedef short bf8 __attribute__((ext_vector_type(8)));
typedef float f4  __attribute__((ext_vector_type(4)));
typedef unsigned int u32;

__device__ __forceinline__ float bf2f(ushort u) {
    return __uint_as_float(((unsigned)u) << 16);
}
__device__ __forceinline__ ushort f2bf(float f) {
    unsigned u = __float_as_uint(f);
    return (ushort)((u + 0x7fffu + ((u >> 16) & 1u)) >> 16);
}
__device__ __forceinline__ float gelu_exact(float x) {
    return 0.5f * x * (1.0f + erff(x * 0.70710678118654752f));
}
__device__ __forceinline__ int clampi(int v) {
    return ((unsigned)v >= (unsigned)NNODE) ? 0 : v;
}
__device__ __forceinline__ int getidx(const int* ei, bool i64, int pos) {
    int v = i64 ? ei[2 * pos] : ei[pos];
    return clampi(v);
}
__device__ __forceinline__ float loadf(const void* p, size_t idx, bool f32) {
    return f32 ? ((const float*)p)[idx] : bf2f(((const ushort*)p)[idx]);
}
__device__ __forceinline__ bf8 load8(const void* p, size_t idx, bool f32) {
    if (f32) {
        const float* fp = (const float*)p + idx;
        f4 lo = *(const f4*)fp, hi = *(const f4*)(fp + 4);
        bf8 r;
        r[0] = (short)f2bf(lo[0]); r[1] = (short)f2bf(lo[1]);
        r[2] = (short)f2bf(lo[2]); r[3] = (short)f2bf(lo[3]);
        r[4] = (short)f2bf(hi[0]); r[5] = (short)f2bf(hi[1]);
        r[6] = (short)f2bf(hi[2]); r[7] = (short)f2bf(hi[3]);
        return r;
    }
    return *(const bf8*)((const ushort*)p + idx);
}
__device__ __forceinline__ void storef(void* p, size_t idx, float v, bool f32) {
    if (f32) ((float*)p)[idx] = v;
    else     ((ushort*)p)[idx] = f2bf(v);
}
__device__ __forceinline__ void fadd_native(float* p, float v) {
    unsafeAtomicAdd(p, v);
}
// async global->LDS, 16B per lane; LDS dest wave-uniform base, HW adds lane*16
__device__ __forceinline__ void gload16(const void* g, void* l) {
    __builtin_amdgcn_global_load_lds(
        (const __attribute__((address_space(1))) void*)g,
        (__attribute__((address_space(3))) void*)l, 16, 0, 0);
}

// ---- runtime dtype detection ----
__global__ void detect_kernel(const u32* __restrict__ h_u32,
                              const u32* __restrict__ ei_u32,
                              u32* __restrict__ flags) {
    if (threadIdx.x == 0 && blockIdx.x == 0) {
        int inwin = 0;
        for (int i = 0; i < 64; ++i) {
            u32 e8 = (h_u32[i] >> 7) & 0xFFu;
            if (e8 >= 100u && e8 <= 150u) ++inwin;
        }
        u32 f32 = (inwin < 40) ? 1u : 0u;
        u32 hi_or = 0;
        for (int j = 0; j < 16; ++j) hi_or |= ei_u32[2 * j + 1];
        u32 i64 = (hi_or == 0u) ? 1u : 0u;
        flags[0] = f32;
        flags[1] = i64;
    }
}

// ---- weight transpose to bf16 n-major ----
__global__ void wt_kernel(const void* __restrict__ W, ushort* __restrict__ WT,
                          int K, int N, const u32* __restrict__ flags) {
    const bool f32 = flags[0] != 0;
    int k = blockIdx.x, n = threadIdx.x;
    if (k < K && n < N)
        WT[(size_t)n * K + k] = f2bf(loadf(W, (size_t)k * N + n, f32));
}

// ---- h convert to bf16 ----
__global__ void hconv_kernel(const void* __restrict__ h, ushort* __restrict__ hb,
                             const u32* __restrict__ flags) {
    const bool f32 = flags[0] != 0;
    int i = blockIdx.x * 256 + threadIdx.x;
    if (i < NNODE * HIDD / 8)
        *(bf8*)&hb[(size_t)i * 8] = load8(h, (size_t)i * 8, f32);
}

// ---- per-dst edge counts ----
__global__ void count_kernel(const int* __restrict__ ei, u32* __restrict__ cnt,
                             const u32* __restrict__ flags) {
    bool i64 = flags[1] != 0;
    int i = blockIdx.x * 256 + threadIdx.x;
    if (i < NEDGE) atomicAdd(&cnt[getidx(ei, i64, NEDGE + i)], 1u);
}

// ---- exclusive prefix scan over cnt -> head ----
__global__ void scan_kernel(const u32* __restrict__ cnt, int* __restrict__ head) {
    __shared__ u32 part[256];
    __shared__ u32 base[256];
    int t = threadIdx.x;
    u32 s = 0;
    for (int j = 0; j < 40; ++j) {
        int i = t * 40 + j;
        if (i < NNODE) s += cnt[i];
    }
    part[t] = s;
    __syncthreads();
    if (t == 0) {
        u32 run = 0;
        for (int i = 0; i < 256; ++i) { base[i] = run; run += part[i]; }
    }
    __syncthreads();
    u32 run = base[t];
    for (int j = 0; j < 40; ++j) {
        int i = t * 40 + j;
        if (i < NNODE) { head[i] = (int)run; run += cnt[i]; }
    }
}

// ---- bucket fill: perm/dsts sorted by dst ----
__global__ void fill_kernel(const int* __restrict__ ei, int* __restrict__ head,
                            int* __restrict__ perm, int* __restrict__ dsts,
                            const u32* __restrict__ flags) {
    bool i64 = flags[1] != 0;
    int i = blockIdx.x * 256 + threadIdx.x;
    if (i < NEDGE) {
        int d = getidx(ei, i64, NEDGE + i);
        int pos = atomicAdd(&head[d], 1);
        perm[pos] = i;
        dsts[pos] = d;
    }
}

// ============ edge update: e_new = LN(e + MLP([h_src|h_dst|e])) ============
// 64 edges/block, 256 thr, 4 waves (wave = 16 rows x 128 cols).
// Async gload_lds double-buffered staging; XOR-swizzled linear LDS.
__global__ __launch_bounds__(256) void edge_kernel(
    const ushort* __restrict__ hb, const void* __restrict__ e,
    const int* __restrict__ ei,
    const ushort* __restrict__ WT1, const void* __restrict__ be1,
    const ushort* __restrict__ WT2, const void* __restrict__ be2,
    const void* __restrict__ neg, const void* __restrict__ neb,
    void* __restrict__ out, const u32* __restrict__ flags)
{
    const bool f32 = flags[0] != 0, i64 = flags[1] != 0;
    __shared__ ushort Asm[2][64 * 64];    // 16 KB  (linear, swizzled)
    __shared__ ushort Bsm[2][128 * 64];   // 32 KB  (linear, swizzled)
    __shared__ ushort Tsm[64 * 136];      // 17.4 KB (padded, normal)

    const int tid = threadIdx.x;
    const int wid = tid >> 6, lane = tid & 63;
    const int l16 = lane & 15, lg = lane >> 4;
    const int edge0 = blockIdx.x * 64;
    const int rm = wid * 16;

    // staging lane geometry: chunk rows 16*wid+8j+(lane>>3), 16B piece (lane&7)
    const int lr = lane >> 3;                 // 0..7 row-in-chunk
    const int c8b = (lane & 7) * 16;          // LDS byte offset in 128B row
    const int ke = ((c8b ^ ((lr & 7) << 4)) >> 1);  // swizzled source elem off

    size_t hsA[2], hdA[2], eA[2];
    #pragma unroll
    for (int j = 0; j < 2; ++j) {
        int r = 16 * wid + 8 * j + lr;
        hsA[j] = (size_t)getidx(ei, i64, edge0 + r) * HIDD;
        hdA[j] = (size_t)getidx(ei, i64, NEDGE + edge0 + r) * HIDD;
        eA[j]  = (size_t)(edge0 + r) * ED;
    }

    f4 acc[8] = {};

    // ---------------- phase 1: K=640 ----------------
    // prologue: stage kc=0
    #pragma unroll
    for (int j = 0; j < 2; ++j)
        gload16(hb + hsA[j] + 0 + ke, &Asm[0][(16 * wid + 8 * j) * 64]);
    #pragma unroll
    for (int c = 0; c < 4; ++c) {
        int n0 = 8 * (4 * wid + c);
        gload16(WT1 + (size_t)(n0 + lr) * CAT + 0 + ke, &Bsm[0][n0 * 64]);
    }
    __syncthreads();

    int cur = 0;
    for (int kc = 0; kc < 10; ++kc) {
        f4 ef[2][2];
        bool regst = false;
        if (kc < 9) {
            int nk = kc + 1;
            // A stage for nk
            if (nk < 4) {
                #pragma unroll
                for (int j = 0; j < 2; ++j)
                    gload16(hb + hsA[j] + nk * 64 + ke, &Asm[cur ^ 1][(16 * wid + 8 * j) * 64]);
            } else if (nk < 8) {
                #pragma unroll
                for (int j = 0; j < 2; ++j)
                    gload16(hb + hdA[j] + (nk - 4) * 64 + ke, &Asm[cur ^ 1][(16 * wid + 8 * j) * 64]);
            } else if (!f32) {
                #pragma unroll
                for (int j = 0; j < 2; ++j)
                    gload16((const ushort*)e + eA[j] + (nk - 8) * 64 + ke, &Asm[cur ^ 1][(16 * wid + 8 * j) * 64]);
            } else {
                regst = true;
                #pragma unroll
                for (int j = 0; j < 2; ++j) {
                    const float* ep = (const float*)e + eA[j] + (nk - 8) * 64 + ke;
                    ef[j][0] = *(const f4*)ep;
                    ef[j][1] = *(const f4*)(ep + 4);
                }
            }
            // B stage for nk
            #pragma unroll
            for (int c = 0; c < 4; ++c) {
                int n0 = 8 * (4 * wid + c);
                gload16(WT1 + (size_t)(n0 + lr) * CAT + nk * 64 + ke, &Bsm[cur ^ 1][n0 * 64]);
            }
        }
        // MFMA on cur
        #pragma unroll
        for (int ks = 0; ks < 2; ++ks) {
            int kb = ks * 64 + lg * 16;
            int ko = ((kb ^ ((l16 & 7) << 4)) >> 1);
            bf8 a = *(const bf8*)&Asm[cur][(rm + l16) * 64 + ko];
            #pragma unroll
            for (int f = 0; f < 8; ++f) {
                bf8 b = *(const bf8*)&Bsm[cur][(f * 16 + l16) * 64 + ko];
                acc[f] = __builtin_amdgcn_mfma_f32_16x16x32_bf16(a, b, acc[f], 0, 0, 0);
            }
        }
        if (regst) {
            #pragma unroll
            for (int j = 0; j < 2; ++j) {
                bf8 w;
                w[0] = (short)f2bf(ef[j][0][0]); w[1] = (short)f2bf(ef[j][0][1]);
                w[2] = (short)f2bf(ef[j][0][2]); w[3] = (short)f2bf(ef[j][0][3]);
                w[4] = (short)f2bf(ef[j][1][0]); w[5] = (short)f2bf(ef[j][1][1]);
                w[6] = (short)f2bf(ef[j][1][2]); w[7] = (short)f2bf(ef[j][1][3]);
                *(bf8*)&Asm[cur ^ 1][(16 * wid + 8 * j + lr) * 64 + (lane & 7) * 8] = w;
            }
        }
        __syncthreads();
        cur ^= 1;
    }

    // epilogue 1: bias + gelu -> Tsm (padded)
    #pragma unroll
    for (int f = 0; f < 8; ++f) {
        float bias = loadf(be1, f * 16 + l16, f32);
        #pragma unroll
        for (int r = 0; r < 4; ++r)
            Tsm[(rm + lg * 4 + r) * 136 + f * 16 + l16] = f2bf(gelu_exact(acc[f][r] + bias));
    }
    // stage phase-2 B (kc2=0) while Tsm settles
    #pragma unroll
    for (int c = 0; c < 4; ++c) {
        int n0 = 8 * (4 * wid + c);
        gload16(WT2 + (size_t)(n0 + lr) * ED + 0 + ke, &Bsm[0][n0 * 64]);
    }
    __syncthreads();

    // ---------------- phase 2: K=128 ----------------
    f4 acc2[8] = {};
    for (int kc2 = 0; kc2 < 2; ++kc2) {
        if (kc2 == 0) {
            #pragma unroll
            for (int c = 0; c < 4; ++c) {
                int n0 = 8 * (4 * wid + c);
                gload16(WT2 + (size_t)(n0 + lr) * ED + 64 + ke, &Bsm[1][n0 * 64]);
            }
        }
        #pragma unroll
        for (int ks = 0; ks < 2; ++ks) {
            int kb = ks * 64 + lg * 16;
            int ko = ((kb ^ ((l16 & 7) << 4)) >> 1);
            bf8 a = *(const bf8*)&Tsm[(rm + l16) * 136 + kc2 * 64 + ks * 32 + lg * 8];
            #pragma unroll
            for (int f = 0; f < 8; ++f) {
                bf8 b = *(const bf8*)&Bsm[kc2][(f * 16 + l16) * 64 + ko];
                acc2[f] = __builtin_amdgcn_mfma_f32_16x16x32_bf16(a, b, acc2[f], 0, 0, 0);
            }
        }
        __syncthreads();
    }

    // epilogue 2: bias + residual (direct global) + LN + store
    float v[8][4];
    #pragma unroll
    for (int f = 0; f < 8; ++f) {
        float bias = loadf(be2, f * 16 + l16, f32);
        #pragma unroll
        for (int r = 0; r < 4; ++r) {
            int row = rm + lg * 4 + r;
            v[f][r] = acc2[f][r] + bias
                    + loadf(e, (size_t)(edge0 + row) * ED + f * 16 + l16, f32);
        }
    }
    #pragma unroll
    for (int r = 0; r < 4; ++r) {
        float s = 0.f;
        #pragma unroll
        for (int f = 0; f < 8; ++f) s += v[f][r];
        s += __shfl_xor(s, 1); s += __shfl_xor(s, 2);
        s += __shfl_xor(s, 4); s += __shfl_xor(s, 8);
        float mu = s * (1.0f / 128.0f);
        float q = 0.f;
        #pragma unroll
        for (int f = 0; f < 8; ++f) { float d = v[f][r] - mu; q += d * d; }
        q += __shfl_xor(q, 1); q += __shfl_xor(q, 2);
        q += __shfl_xor(q, 4); q += __shfl_xor(q, 8);
        float rstd = rsqrtf(q * (1.0f / 128.0f) + 1e-5f);
        int row = edge0 + rm + lg * 4 + r;
        #pragma unroll
        for (int f = 0; f < 8; ++f) {
            int col = f * 16 + l16;
            float y = (v[f][r] - mu) * rstd * loadf(neg, col, f32) + loadf(neb, col, f32);
            storef(out, (size_t)NNODE * HIDD + (size_t)row * ED + col, y, f32);
        }
    }
}

// ============ node phase 1 (dst-sorted): S[dst] += gelu(X@Wv1+bv1) ============
// 64 edges/block, 256 thr, 4 waves (wave = 64 rows x 64 cols).
__global__ __launch_bounds__(256) void node1_kernel(
    const ushort* __restrict__ hb, const void* __restrict__ out /*e_new f32*/,
    const int* __restrict__ ei, const int* __restrict__ perm,
    const int* __restrict__ dsts,
    const ushort* __restrict__ WTv1, const void* __restrict__ bv1,
    float* __restrict__ S, const u32* __restrict__ flags)
{
    const bool f32 = flags[0] != 0, i64 = flags[1] != 0;
    __shared__ ushort Asm[2][64 * 64];    // 16 KB
    __shared__ ushort Bsm[2][256 * 64];   // 64 KB

    const int tid = threadIdx.x;
    const int wid = tid >> 6, lane = tid & 63;
    const int l16 = lane & 15, lg = lane >> 4;
    const int edge0 = blockIdx.x * 64;
    const size_t EOFF = (size_t)NNODE * HIDD;

    const int lr = lane >> 3;
    const int c8b = (lane & 7) * 16;
    const int ke = ((c8b ^ ((lr & 7) << 4)) >> 1);

    size_t hsA[2], hdA[2], enA[2];
    #pragma unroll
    for (int j = 0; j < 2; ++j) {
        int r = 16 * wid + 8 * j + lr;
        int eid = perm[edge0 + r];
        hsA[j] = (size_t)getidx(ei, i64, eid) * HIDD;
        hdA[j] = (size_t)getidx(ei, i64, NEDGE + eid) * HIDD;
        enA[j] = EOFF + (size_t)eid * ED;
    }

    f4 acc[4][4] = {};

    // prologue: stage kc=0
    #pragma unroll
    for (int j = 0; j < 2; ++j)
        gload16(hb + hsA[j] + 0 + ke, &Asm[0][(16 * wid + 8 * j) * 64]);
    #pragma unroll
    for (int c = 0; c < 8; ++c) {
        int n0 = 8 * (8 * wid + c);
        gload16(WTv1 + (size_t)(n0 + lr) * CAT + 0 + ke, &Bsm[0][n0 * 64]);
    }
    __syncthreads();

    int cur = 0;
    for (int kc = 0; kc < 10; ++kc) {
        f4 ef[2][2];
        bool regst = false;
        if (kc < 9) {
            int nk = kc + 1;
            if (nk < 4) {
                #pragma unroll
                for (int j = 0; j < 2; ++j)
                    gload16(hb + hsA[j] + nk * 64 + ke, &Asm[cur ^ 1][(16 * wid + 8 * j) * 64]);
            } else if (nk < 8) {
                #pragma unroll
                for (int j = 0; j < 2; ++j)
                    gload16(hb + hdA[j] + (nk - 4) * 64 + ke, &Asm[cur ^ 1][(16 * wid + 8 * j) * 64]);
            } else {
                // e_new always f32 in out
                regst = true;
                #pragma unroll
                for (int j = 0; j < 2; ++j) {
                    const float* ep = (const float*)out + enA[j] + (nk - 8) * 64 + ke;
                    ef[j][0] = *(const f4*)ep;
                    ef[j][1] = *(const f4*)(ep + 4);
                }
            }
            #pragma unroll
            for (int c = 0; c < 8; ++c) {
                int n0 = 8 * (8 * wid + c);
                gload16(WTv1 + (size_t)(n0 + lr) * CAT + nk * 64 + ke, &Bsm[cur ^ 1][n0 * 64]);
            }
        }
        #pragma unroll
        for (int ks = 0; ks < 2; ++ks) {
            int kb = ks * 64 + lg * 16;
            int ko = ((kb ^ ((l16 & 7) << 4)) >> 1);
            bf8 a[4], b[4];
            #pragma unroll
            for (int ai = 0; ai < 4; ++ai)
                a[ai] = *(const bf8*)&Asm[cur][(ai * 16 + l16) * 64 + ko];
            #pragma unroll
            for (int bi = 0; bi < 4; ++bi)
                b[bi] = *(const bf8*)&Bsm[cur][(wid * 64 + bi * 16 + l16) * 64 + ko];
            #pragma unroll
            for (int ai = 0; ai < 4; ++ai)
                #pragma unroll
                for (int bi = 0; bi < 4; ++bi)
                    acc[ai][bi] = __builtin_amdgcn_mfma_f32_16x16x32_bf16(a[ai], b[bi], acc[ai][bi], 0, 0, 0);
        }
        if (regst) {
            #pragma unroll
            for (int j = 0; j < 2; ++j) {
                bf8 w;
                w[0] = (short)f2bf(ef[j][0][0]); w[1] = (short)f2bf(ef[j][0][1]);
                w[2] = (short)f2bf(ef[j][0][2]); w[3] = (short)f2bf(ef[j][0][3]);
                w[4] = (short)f2bf(ef[j][1][0]); w[5] = (short)f2bf(ef[j][1][1]);
                w[6] = (short)f2bf(ef[j][1][2]); w[7] = (short)f2bf(ef[j][1][3]);
                *(bf8*)&Asm[cur ^ 1][(16 * wid + 8 * j + lr) * 64 + (lane & 7) * 8] = w;
            }
        }
        __syncthreads();
        cur ^= 1;
    }

    // gelu + run-merged scatter (dsts sorted)
    float bias[4];
    #pragma unroll
    for (int bi = 0; bi < 4; ++bi) bias[bi] = loadf(bv1, wid * 64 + bi * 16 + l16, f32);
    #pragma unroll
    for (int ai = 0; ai < 4; ++ai) {
        int p0 = edge0 + ai * 16 + lg * 4;
        int d0 = dsts[p0 + 0], d1 = dsts[p0 + 1];
        int d2 = dsts[p0 + 2], d3 = dsts[p0 + 3];
        #pragma unroll
        for (int bi = 0; bi < 4; ++bi) {
            int col = wid * 64 + bi * 16 + l16;
            float v0 = gelu_exact(acc[ai][bi][0] + bias[bi]);
            float v1 = gelu_exact(acc[ai][bi][1] + bias[bi]);
            float v2 = gelu_exact(acc[ai][bi][2] + bias[bi]);
            float v3 = gelu_exact(acc[ai][bi][3] + bias[bi]);
            float s = v0; int d = d0;
            if (d1 == d) s += v1; else { fadd_native(&S[(size_t)d * HIDD + col], s); d = d1; s = v1; }
            if (d2 == d) s += v2; else { fadd_native(&S[(size_t)d * HIDD + col], s); d = d2; s = v2; }
            if (d3 == d) s += v3; else { fadd_native(&S[(size_t)d * HIDD + col], s); d = d3; s = v3; }
            fadd_native(&S[(size_t)d * HIDD + col], s);
        }
    }
}

// ---- node phase 2 + LN ----
__global__ __launch_bounds__(256) void hn_gemm_kernel(
    const float* __restrict__ S, const ushort* __restrict__ WTv2,
    const void* __restrict__ bv2, const u32* __restrict__ cnt,
    const void* __restrict__ h,
    const void* __restrict__ nvg, const void* __restrict__ nvb,
    void* __restrict__ out, const u32* __restrict__ flags)
{
    const bool f32 = flags[0] != 0;
    constexpr int LDV = 260;
    __shared__ float Vsm[64 * LDV];

    const int tid = threadIdx.x;
    const int wid = tid >> 6, lane = tid & 63;
    const int l16 = lane & 15, lg = lane >> 4;
    const int node0 = blockIdx.x * 64;
    const int n0 = wid * 64;

    size_t ra[4];
    #pragma unroll
    for (int ai = 0; ai < 4; ++ai) {
        int row = node0 + ai * 16 + l16;
        ra[ai] = (size_t)(row < NNODE ? row : NNODE - 1) * HIDD;
    }
    int bb[4];
    #pragma unroll
    for (int bi = 0; bi < 4; ++bi) bb[bi] = (n0 + bi * 16 + l16) * HIDD;

    f4 acc[4][4] = {};
    for (int kc = 0; kc < 4; ++kc) {
        #pragma unroll
        for (int ks = 0; ks < 2; ++ks) {
            int kk = kc * 64 + ks * 32 + lg * 8;
            bf8 b[4];
            #pragma unroll
            for (int bi = 0; bi < 4; ++bi) b[bi] = *(const bf8*)&WTv2[bb[bi] + kk];
            #pragma unroll
            for (int ai = 0; ai < 4; ++ai) {
                bf8 a = load8(S, ra[ai] + kk, true);
                #pragma unroll
                for (int bi = 0; bi < 4; ++bi)
                    acc[ai][bi] = __builtin_amdgcn_mfma_f32_16x16x32_bf16(a, b[bi], acc[ai][bi], 0, 0, 0);
            }
        }
    }

    #pragma unroll
    for (int bi = 0; bi < 4; ++bi) {
        int col = n0 + bi * 16 + l16;
        float b2 = loadf(bv2, col, f32);
        #pragma unroll
        for (int ai = 0; ai < 4; ++ai)
            #pragma unroll
            for (int r = 0; r < 4; ++r) {
                int rowl = ai * 16 + lg * 4 + r;
                int gr = node0 + rowl;
                int grc = gr < NNODE ? gr : NNODE - 1;
                float c = (float)cnt[grc];
                float inv = 1.0f / fmaxf(c, 1.0f);
                float val = (acc[ai][bi][r] + c * b2) * inv
                          + loadf(h, (size_t)grc * HIDD + col, f32);
                Vsm[rowl * LDV + col] = val;
            }
    }
    __syncthreads();

    #pragma unroll
    for (int rr = 0; rr < 4; ++rr) {
        int rowl = wid * 16 + lg * 4 + rr;
        int gr = node0 + rowl;
        float x[16];
        #pragma unroll
        for (int f = 0; f < 16; ++f) x[f] = Vsm[rowl * LDV + f * 16 + l16];
        float s = 0.f;
        #pragma unroll
        for (int f = 0; f < 16; ++f) s += x[f];
        s += __shfl_xor(s, 1); s += __shfl_xor(s, 2);
        s += __shfl_xor(s, 4); s += __shfl_xor(s, 8);
        float mu = s * (1.0f / 256.0f);
        float q = 0.f;
        #pragma unroll
        for (int f = 0; f < 16; ++f) { float d = x[f] - mu; q += d * d; }
        q += __shfl_xor(q, 1); q += __shfl_xor(q, 2);
        q += __shfl_xor(q, 4); q += __shfl_xor(q, 8);
        float rstd = rsqrtf(q * (1.0f / 256.0f) + 1e-5f);
        if (gr < NNODE) {
            #pragma unroll
            for (int f = 0; f < 16; ++f) {
                int col = f * 16 + l16;
                float y = (x[f] - mu) * rstd * loadf(nvg, col, f32) + loadf(nvb, col, f32);
                storef(out, (size_t)gr * HIDD + col, y, f32);
            }
        }
    }
}

extern "C" void kernel_launch(void* const* d_in, const int* in_sizes, int n_in,
                              void* d_out, int out_size, void* d_ws, size_t ws_size,
                              hipStream_t stream)
{
    (void)in_sizes; (void)n_in; (void)out_size; (void)ws_size;
    const void* h   = d_in[0];
    const void* e   = d_in[1];
    const int*  ei  = (const int*)d_in[2];
    const void* We1 = d_in[3];
    const void* be1 = d_in[4];
    const void* We2 = d_in[5];
    const void* be2 = d_in[6];
    const void* Wv1 = d_in[7];
    const void* bv1 = d_in[8];
    const void* Wv2 = d_in[9];
    const void* bv2 = d_in[10];
    const void* neg = d_in[11];
    const void* neb = d_in[12];
    const void* nvg = d_in[13];
    const void* nvb = d_in[14];

    char* ws = (char*)d_ws;
    u32*   flags = (u32*)ws;
    float* S     = (float*)(ws + 256);
    u32*   cnt   = (u32*)(ws + 256 + (size_t)NNODE * HIDD * 4);
    size_t off = 256 + (size_t)NNODE * HIDD * 4 + ((size_t)NNODE * 4 + 255) / 256 * 256;
    int*   head = (int*)(ws + off);                 off += ((size_t)NNODE * 4 + 255) / 256 * 256;
    int*   perm = (int*)(ws + off);                 off += (size_t)NEDGE * 4;
    int*   dsts = (int*)(ws + off);                 off += (size_t)NEDGE * 4;
    ushort* WT1  = (ushort*)(ws + off);
    ushort* WT2  = WT1 + (size_t)ED * CAT;
    ushort* WTv1 = WT2 + (size_t)ED * ED;
    ushort* WTv2 = WTv1 + (size_t)HIDD * CAT;
    ushort* hb   = WTv2 + (size_t)HIDD * HIDD;

    hipMemsetAsync(S, 0, (size_t)NNODE * HIDD * 4 + (size_t)NNODE * 4, stream);
    detect_kernel<<<1, 64, 0, stream>>>((const u32*)h, (const u32*)ei, flags);

    wt_kernel<<<CAT,  ED,   0, stream>>>(We1, WT1, CAT, ED, flags);
    wt_kernel<<<ED,   ED,   0, stream>>>(We2, WT2, ED, ED, flags);
    wt_kernel<<<CAT,  HIDD, 0, stream>>>(Wv1, WTv1, CAT, HIDD, flags);
    wt_kernel<<<HIDD, HIDD, 0, stream>>>(Wv2, WTv2, HIDD, HIDD, flags);
    hconv_kernel<<<(NNODE * HIDD / 8 + 255) / 256, 256, 0, stream>>>(h, hb, flags);
    count_kernel<<<(NEDGE + 255) / 256, 256, 0, stream>>>(ei, cnt, flags);
    scan_kernel<<<1, 256, 0, stream>>>(cnt, head);
    fill_kernel<<<(NEDGE + 255) / 256, 256, 0, stream>>>(ei, head, perm, dsts, flags);

    edge_kernel<<<NEDGE / 64, 256, 0, stream>>>(hb, e, ei, WT1, be1, WT2, be2,
                                                neg, neb, d_out, flags);
    node1_kernel<<<NEDGE / 64, 256, 0, stream>>>(hb, d_out, ei, perm, dsts,
                                                 WTv1, bv1, S, flags);
    hn_gemm_kernel<<<(NNODE + 63) / 64, 256, 0, stream>>>(S, WTv2, bv2, cnt, h,
                                                          nvg, nvb, d_out, flags);
}

// Round 10
// 430.018 us; speedup vs baseline: 1.0043x; 1.0043x over previous
//
#include <hip/hip_runtime.h>
#include <hip/hip_bf16.h>

#define NNODE 10000
#define NEDGE 160000
#define HIDD  256
#define ED    128
#define CAT   640

typedef short bf8 __attribute__((ext_vector_type(8)));
typedef float f4  __attribute__((ext_vector_type(4)));
typedef unsigned int u32;

__device__ __forceinline__ float bf2f(ushort u) {
    return __uint_as_float(((unsigned)u) << 16);
}
__device__ __forceinline__ ushort f2bf(float f) {
    unsigned u = __float_as_uint(f);
    return (ushort)((u + 0x7fffu + ((u >> 16) & 1u)) >> 16);
}
__device__ __forceinline__ float gelu_exact(float x) {
    return 0.5f * x * (1.0f + erff(x * 0.70710678118654752f));
}
__device__ __forceinline__ int clampi(int v) {
    return ((unsigned)v >= (unsigned)NNODE) ? 0 : v;
}
__device__ __forceinline__ int getidx(const int* ei, bool i64, int pos) {
    int v = i64 ? ei[2 * pos] : ei[pos];
    return clampi(v);
}
__device__ __forceinline__ float loadf(const void* p, size_t idx, bool f32) {
    return f32 ? ((const float*)p)[idx] : bf2f(((const ushort*)p)[idx]);
}
__device__ __forceinline__ bf8 load8(const void* p, size_t idx, bool f32) {
    if (f32) {
        const float* fp = (const float*)p + idx;
        f4 lo = *(const f4*)fp, hi = *(const f4*)(fp + 4);
        bf8 r;
        r[0] = (short)f2bf(lo[0]); r[1] = (short)f2bf(lo[1]);
        r[2] = (short)f2bf(lo[2]); r[3] = (short)f2bf(lo[3]);
        r[4] = (short)f2bf(hi[0]); r[5] = (short)f2bf(hi[1]);
        r[6] = (short)f2bf(hi[2]); r[7] = (short)f2bf(hi[3]);
        return r;
    }
    return *(const bf8*)((const ushort*)p + idx);
}
__device__ __forceinline__ void storef(void* p, size_t idx, float v, bool f32) {
    if (f32) ((float*)p)[idx] = v;
    else     ((ushort*)p)[idx] = f2bf(v);
}
__device__ __forceinline__ void fadd_native(float* p, float v) {
    unsafeAtomicAdd(p, v);
}

// ---- runtime dtype detection ----
__global__ void detect_kernel(const u32* __restrict__ h_u32,
                              const u32* __restrict__ ei_u32,
                              u32* __restrict__ flags) {
    if (threadIdx.x == 0 && blockIdx.x == 0) {
        int inwin = 0;
        for (int i = 0; i < 64; ++i) {
            u32 e8 = (h_u32[i] >> 7) & 0xFFu;
            if (e8 >= 100u && e8 <= 150u) ++inwin;
        }
        u32 f32 = (inwin < 40) ? 1u : 0u;
        u32 hi_or = 0;
        for (int j = 0; j < 16; ++j) hi_or |= ei_u32[2 * j + 1];
        u32 i64 = (hi_or == 0u) ? 1u : 0u;
        flags[0] = f32;
        flags[1] = i64;
    }
}

// ---- weight sub-block transpose to bf16 n-major: WT[n][k] = W[k0+k][n] ----
__global__ void wt_kernel(const void* __restrict__ W, ushort* __restrict__ WT,
                          int k0, int K, int N, int Wld,
                          const u32* __restrict__ flags) {
    const bool f32 = flags[0] != 0;
    int k = blockIdx.x, n = threadIdx.x;
    if (k < K && n < N)
        WT[(size_t)n * K + k] = f2bf(loadf(W, (size_t)(k0 + k) * Wld + n, f32));
}

// ---- h convert to bf16 ----
__global__ void hconv_kernel(const void* __restrict__ h, ushort* __restrict__ hb,
                             const u32* __restrict__ flags) {
    const bool f32 = flags[0] != 0;
    int i = blockIdx.x * 256 + threadIdx.x;
    if (i < NNODE * HIDD / 8)
        *(bf8*)&hb[(size_t)i * 8] = load8(h, (size_t)i * 8, f32);
}

// ---- per-dst edge counts ----
__global__ void count_kernel(const int* __restrict__ ei, u32* __restrict__ cnt,
                             const u32* __restrict__ flags) {
    bool i64 = flags[1] != 0;
    int i = blockIdx.x * 256 + threadIdx.x;
    if (i < NEDGE) atomicAdd(&cnt[getidx(ei, i64, NEDGE + i)], 1u);
}

// ---- exclusive prefix scan over cnt -> head ----
__global__ void scan_kernel(const u32* __restrict__ cnt, int* __restrict__ head) {
    __shared__ u32 part[256];
    __shared__ u32 base[256];
    int t = threadIdx.x;
    u32 s = 0;
    for (int j = 0; j < 40; ++j) {
        int i = t * 40 + j;
        if (i < NNODE) s += cnt[i];
    }
    part[t] = s;
    __syncthreads();
    if (t == 0) {
        u32 run = 0;
        for (int i = 0; i < 256; ++i) { base[i] = run; run += part[i]; }
    }
    __syncthreads();
    u32 run = base[t];
    for (int j = 0; j < 40; ++j) {
        int i = t * 40 + j;
        if (i < NNODE) { head[i] = (int)run; run += cnt[i]; }
    }
}

// ---- bucket fill: perm/dsts sorted by dst ----
__global__ void fill_kernel(const int* __restrict__ ei, int* __restrict__ head,
                            int* __restrict__ perm, int* __restrict__ dsts,
                            const u32* __restrict__ flags) {
    bool i64 = flags[1] != 0;
    int i = blockIdx.x * 256 + threadIdx.x;
    if (i < NEDGE) {
        int d = getidx(ei, i64, NEDGE + i);
        int pos = atomicAdd(&head[d], 1);
        perm[pos] = i;
        dsts[pos] = d;
    }
}

// ---- node-level projection GEMM: O[10000][NB*64] = bf16(hb @ WT^T), K=256 ----
template<int NB>
__global__ __launch_bounds__(256) void qp_kernel(
    const ushort* __restrict__ hb, const ushort* __restrict__ WT,
    ushort* __restrict__ O)
{
    const int tid = threadIdx.x;
    const int wid = tid >> 6, lane = tid & 63;
    const int l16 = lane & 15, lg = lane >> 4;
    const int node0 = blockIdx.x * 64;
    const int N = NB * 64;
    const int n0 = wid * (NB * 16);

    size_t ra[4];
    #pragma unroll
    for (int ai = 0; ai < 4; ++ai) {
        int row = node0 + ai * 16 + l16;
        ra[ai] = (size_t)(row < NNODE ? row : NNODE - 1) * HIDD;
    }
    int bb[NB];
    #pragma unroll
    for (int bi = 0; bi < NB; ++bi) bb[bi] = (n0 + bi * 16 + l16) * HIDD;

    f4 acc[4][NB] = {};
    for (int kc = 0; kc < 4; ++kc) {
        #pragma unroll
        for (int ks = 0; ks < 2; ++ks) {
            int kk = kc * 64 + ks * 32 + lg * 8;
            bf8 b[NB];
            #pragma unroll
            for (int bi = 0; bi < NB; ++bi) b[bi] = *(const bf8*)&WT[bb[bi] + kk];
            #pragma unroll
            for (int ai = 0; ai < 4; ++ai) {
                bf8 a = *(const bf8*)&hb[ra[ai] + kk];
                #pragma unroll
                for (int bi = 0; bi < NB; ++bi)
                    acc[ai][bi] = __builtin_amdgcn_mfma_f32_16x16x32_bf16(a, b[bi], acc[ai][bi], 0, 0, 0);
            }
        }
    }
    #pragma unroll
    for (int bi = 0; bi < NB; ++bi) {
        int col = n0 + bi * 16 + l16;
        #pragma unroll
        for (int ai = 0; ai < 4; ++ai)
            #pragma unroll
            for (int r = 0; r < 4; ++r) {
                int gr = node0 + ai * 16 + lg * 4 + r;
                if (gr < NNODE) O[(size_t)gr * N + col] = f2bf(acc[ai][bi][r]);
            }
    }
}

// ============ edge update: e_new = LN(e + MLP2(gelu(e@C1 + Qa[src]+Qb[dst]+b1))) ============
__global__ __launch_bounds__(256) void edge_kernel(
    const void* __restrict__ e, const int* __restrict__ ei,
    const ushort* __restrict__ WT1c, const void* __restrict__ be1,
    const ushort* __restrict__ WT2, const void* __restrict__ be2,
    const ushort* __restrict__ Qab,
    const void* __restrict__ neg, const void* __restrict__ neb,
    void* __restrict__ out, const u32* __restrict__ flags)
{
    const bool f32 = flags[0] != 0, i64 = flags[1] != 0;
    __shared__ ushort Asm[64 * 72];
    __shared__ ushort Bsm[128 * 72];
    __shared__ ushort Tsm[64 * 136];

    const int tid = threadIdx.x;
    const int wid = tid >> 6, lane = tid & 63;
    const int l16 = lane & 15, lg = lane >> 4;
    const int edge0 = blockIdx.x * 64;
    const int rm = wid * 16;

    // phase 1: T = e @ C1^T, K=128
    f4 acc[8] = {};
    for (int kc = 0; kc < 2; ++kc) {
        __syncthreads();
        #pragma unroll
        for (int half = 0; half < 2; ++half) {
            int slot = tid + half * 256;
            int r = slot >> 3, c8 = (slot & 7) * 8;
            *(bf8*)&Asm[r * 72 + c8] = load8(e, (size_t)(edge0 + r) * ED + kc * 64 + c8, f32);
        }
        #pragma unroll
        for (int it = 0; it < 4; ++it) {
            int slot = tid + it * 256;
            int n = slot >> 3, c8 = (slot & 7) * 8;
            *(bf8*)&Bsm[n * 72 + c8] = *(const bf8*)&WT1c[n * 128 + kc * 64 + c8];
        }
        __syncthreads();
        #pragma unroll
        for (int ks = 0; ks < 2; ++ks) {
            bf8 a = *(const bf8*)&Asm[(rm + l16) * 72 + ks * 32 + lg * 8];
            #pragma unroll
            for (int f = 0; f < 8; ++f) {
                bf8 b = *(const bf8*)&Bsm[(f * 16 + l16) * 72 + ks * 32 + lg * 8];
                acc[f] = __builtin_amdgcn_mfma_f32_16x16x32_bf16(a, b, acc[f], 0, 0, 0);
            }
        }
    }

    // epilogue 1: + be1 + Qa[src] + Qb[dst], gelu -> Tsm
    int sidx[4], didx[4];
    #pragma unroll
    for (int r = 0; r < 4; ++r) {
        int grow = edge0 + rm + lg * 4 + r;
        sidx[r] = getidx(ei, i64, grow);
        didx[r] = getidx(ei, i64, NEDGE + grow);
    }
    #pragma unroll
    for (int f = 0; f < 8; ++f) {
        int col = f * 16 + l16;
        float bias = loadf(be1, col, f32);
        #pragma unroll
        for (int r = 0; r < 4; ++r) {
            float val = acc[f][r] + bias
                      + bf2f(Qab[(size_t)sidx[r] * 256 + col])
                      + bf2f(Qab[(size_t)didx[r] * 256 + 128 + col]);
            Tsm[(rm + lg * 4 + r) * 136 + col] = f2bf(gelu_exact(val));
        }
    }

    // phase 2: T2 = T1 @ We2, K=128
    f4 acc2[8] = {};
    for (int kc = 0; kc < 2; ++kc) {
        __syncthreads();
        #pragma unroll
        for (int it = 0; it < 4; ++it) {
            int slot = tid + it * 256;
            int n = slot >> 3, c8 = (slot & 7) * 8;
            *(bf8*)&Bsm[n * 72 + c8] = *(const bf8*)&WT2[n * 128 + kc * 64 + c8];
        }
        __syncthreads();
        #pragma unroll
        for (int ks = 0; ks < 2; ++ks) {
            bf8 a = *(const bf8*)&Tsm[(rm + l16) * 136 + kc * 64 + ks * 32 + lg * 8];
            #pragma unroll
            for (int f = 0; f < 8; ++f) {
                bf8 b = *(const bf8*)&Bsm[(f * 16 + l16) * 72 + ks * 32 + lg * 8];
                acc2[f] = __builtin_amdgcn_mfma_f32_16x16x32_bf16(a, b, acc2[f], 0, 0, 0);
            }
        }
    }

    // epilogue 2: + be2 + e residual, LN over 128, store
    float v[8][4];
    #pragma unroll
    for (int f = 0; f < 8; ++f) {
        int col = f * 16 + l16;
        float bias = loadf(be2, col, f32);
        #pragma unroll
        for (int r = 0; r < 4; ++r) {
            int row = rm + lg * 4 + r;
            v[f][r] = acc2[f][r] + bias
                    + loadf(e, (size_t)(edge0 + row) * ED + col, f32);
        }
    }
    #pragma unroll
    for (int r = 0; r < 4; ++r) {
        float s = 0.f;
        #pragma unroll
        for (int f = 0; f < 8; ++f) s += v[f][r];
        s += __shfl_xor(s, 1); s += __shfl_xor(s, 2);
        s += __shfl_xor(s, 4); s += __shfl_xor(s, 8);
        float mu = s * (1.0f / 128.0f);
        float q = 0.f;
        #pragma unroll
        for (int f = 0; f < 8; ++f) { float d = v[f][r] - mu; q += d * d; }
        q += __shfl_xor(q, 1); q += __shfl_xor(q, 2);
        q += __shfl_xor(q, 4); q += __shfl_xor(q, 8);
        float rstd = rsqrtf(q * (1.0f / 128.0f) + 1e-5f);
        int row = edge0 + rm + lg * 4 + r;
        #pragma unroll
        for (int f = 0; f < 8; ++f) {
            int col = f * 16 + l16;
            float y = (v[f][r] - mu) * rstd * loadf(neg, col, f32) + loadf(neb, col, f32);
            storef(out, (size_t)NNODE * HIDD + (size_t)row * ED + col, y, f32);
        }
    }
}

// ====== node phase 1 (dst-sorted): S[dst] += gelu(e_new@Wc + Pa[src]+Pb[dst]+bv1) ======
__global__ __launch_bounds__(256) void node1_kernel(
    const void* __restrict__ out /* e_new source */, const int* __restrict__ ei,
    const int* __restrict__ perm, const int* __restrict__ dsts,
    const ushort* __restrict__ WvcT, const void* __restrict__ bv1,
    const ushort* __restrict__ Pab,
    float* __restrict__ S, const u32* __restrict__ flags)
{
    const bool f32 = flags[0] != 0, i64 = flags[1] != 0;
    __shared__ ushort Asm[64 * 72];
    __shared__ ushort Bsm[256 * 72];

    const int tid = threadIdx.x;
    const int wid = tid >> 6, lane = tid & 63;
    const int l16 = lane & 15, lg = lane >> 4;
    const int edge0 = blockIdx.x * 64;
    const size_t EOFF = (size_t)NNODE * HIDD;

    int eidh[2];
    #pragma unroll
    for (int j = 0; j < 2; ++j) eidh[j] = perm[edge0 + ((tid + j * 256) >> 3)];

    f4 acc[4][4] = {};
    for (int kc = 0; kc < 2; ++kc) {
        __syncthreads();
        #pragma unroll
        for (int j = 0; j < 2; ++j) {
            int slot = tid + j * 256;
            int r = slot >> 3, c8 = (slot & 7) * 8;
            *(bf8*)&Asm[r * 72 + c8] = load8(out, EOFF + (size_t)eidh[j] * ED + kc * 64 + c8, f32);
        }
        #pragma unroll
        for (int it = 0; it < 8; ++it) {
            int slot = tid + it * 256;
            int n = slot >> 3, c8 = (slot & 7) * 8;
            *(bf8*)&Bsm[n * 72 + c8] = *(const bf8*)&WvcT[n * 128 + kc * 64 + c8];
        }
        __syncthreads();
        #pragma unroll
        for (int ks = 0; ks < 2; ++ks) {
            bf8 a[4], b[4];
            #pragma unroll
            for (int ai = 0; ai < 4; ++ai)
                a[ai] = *(const bf8*)&Asm[(ai * 16 + l16) * 72 + ks * 32 + lg * 8];
            #pragma unroll
            for (int bi = 0; bi < 4; ++bi)
                b[bi] = *(const bf8*)&Bsm[(wid * 64 + bi * 16 + l16) * 72 + ks * 32 + lg * 8];
            #pragma unroll
            for (int ai = 0; ai < 4; ++ai)
                #pragma unroll
                for (int bi = 0; bi < 4; ++bi)
                    acc[ai][bi] = __builtin_amdgcn_mfma_f32_16x16x32_bf16(a[ai], b[bi], acc[ai][bi], 0, 0, 0);
        }
    }

    // epilogue: + bv1 + Pa[src] + Pb[dst], gelu, run-merged scatter
    float bias[4];
    #pragma unroll
    for (int bi = 0; bi < 4; ++bi) bias[bi] = loadf(bv1, wid * 64 + bi * 16 + l16, f32);
    #pragma unroll
    for (int ai = 0; ai < 4; ++ai) {
        int p0 = edge0 + ai * 16 + lg * 4;
        int d0 = dsts[p0 + 0], d1 = dsts[p0 + 1];
        int d2 = dsts[p0 + 2], d3 = dsts[p0 + 3];
        int s0 = getidx(ei, i64, perm[p0 + 0]);
        int s1 = getidx(ei, i64, perm[p0 + 1]);
        int s2 = getidx(ei, i64, perm[p0 + 2]);
        int s3 = getidx(ei, i64, perm[p0 + 3]);
        #pragma unroll
        for (int bi = 0; bi < 4; ++bi) {
            int col = wid * 64 + bi * 16 + l16;
            float v0 = gelu_exact(acc[ai][bi][0] + bias[bi]
                     + bf2f(Pab[(size_t)s0 * 512 + col])
                     + bf2f(Pab[(size_t)d0 * 512 + 256 + col]));
            float v1 = gelu_exact(acc[ai][bi][1] + bias[bi]
                     + bf2f(Pab[(size_t)s1 * 512 + col])
                     + bf2f(Pab[(size_t)d1 * 512 + 256 + col]));
            float v2 = gelu_exact(acc[ai][bi][2] + bias[bi]
                     + bf2f(Pab[(size_t)s2 * 512 + col])
                     + bf2f(Pab[(size_t)d2 * 512 + 256 + col]));
            float v3 = gelu_exact(acc[ai][bi][3] + bias[bi]
                     + bf2f(Pab[(size_t)s3 * 512 + col])
                     + bf2f(Pab[(size_t)d3 * 512 + 256 + col]));
            float s = v0; int d = d0;
            if (d1 == d) s += v1; else { fadd_native(&S[(size_t)d * HIDD + col], s); d = d1; s = v1; }
            if (d2 == d) s += v2; else { fadd_native(&S[(size_t)d * HIDD + col], s); d = d2; s = v2; }
            if (d3 == d) s += v3; else { fadd_native(&S[(size_t)d * HIDD + col], s); d = d3; s = v3; }
            fadd_native(&S[(size_t)d * HIDD + col], s);
        }
    }
}

// ---- node phase 2 + LN: h_new = LN(h + (S@Wv2 + cnt*bv2)/max(cnt,1)) ----
__global__ __launch_bounds__(256) void hn_gemm_kernel(
    const float* __restrict__ S, const ushort* __restrict__ WTv2,
    const void* __restrict__ bv2, const u32* __restrict__ cnt,
    const void* __restrict__ h,
    const void* __restrict__ nvg, const void* __restrict__ nvb,
    void* __restrict__ out, const u32* __restrict__ flags)
{
    const bool f32 = flags[0] != 0;
    constexpr int LDV = 260;
    __shared__ float Vsm[64 * LDV];

    const int tid = threadIdx.x;
    const int wid = tid >> 6, lane = tid & 63;
    const int l16 = lane & 15, lg = lane >> 4;
    const int node0 = blockIdx.x * 64;
    const int n0 = wid * 64;

    size_t ra[4];
    #pragma unroll
    for (int ai = 0; ai < 4; ++ai) {
        int row = node0 + ai * 16 + l16;
        ra[ai] = (size_t)(row < NNODE ? row : NNODE - 1) * HIDD;
    }
    int bb[4];
    #pragma unroll
    for (int bi = 0; bi < 4; ++bi) bb[bi] = (n0 + bi * 16 + l16) * HIDD;

    f4 acc[4][4] = {};
    for (int kc = 0; kc < 4; ++kc) {
        #pragma unroll
        for (int ks = 0; ks < 2; ++ks) {
            int kk = kc * 64 + ks * 32 + lg * 8;
            bf8 b[4];
            #pragma unroll
            for (int bi = 0; bi < 4; ++bi) b[bi] = *(const bf8*)&WTv2[bb[bi] + kk];
            #pragma unroll
            for (int ai = 0; ai < 4; ++ai) {
                bf8 a = load8(S, ra[ai] + kk, true);
                #pragma unroll
                for (int bi = 0; bi < 4; ++bi)
                    acc[ai][bi] = __builtin_amdgcn_mfma_f32_16x16x32_bf16(a, b[bi], acc[ai][bi], 0, 0, 0);
            }
        }
    }

    #pragma unroll
    for (int bi = 0; bi < 4; ++bi) {
        int col = n0 + bi * 16 + l16;
        float b2 = loadf(bv2, col, f32);
        #pragma unroll
        for (int ai = 0; ai < 4; ++ai)
            #pragma unroll
            for (int r = 0; r < 4; ++r) {
                int rowl = ai * 16 + lg * 4 + r;
                int gr = node0 + rowl;
                int grc = gr < NNODE ? gr : NNODE - 1;
                float c = (float)cnt[grc];
                float inv = 1.0f / fmaxf(c, 1.0f);
                float val = (acc[ai][bi][r] + c * b2) * inv
                          + loadf(h, (size_t)grc * HIDD + col, f32);
                Vsm[rowl * LDV + col] = val;
            }
    }
    __syncthreads();

    #pragma unroll
    for (int rr = 0; rr < 4; ++rr) {
        int rowl = wid * 16 + lg * 4 + rr;
        int gr = node0 + rowl;
        float x[16];
        #pragma unroll
        for (int f = 0; f < 16; ++f) x[f] = Vsm[rowl * LDV + f * 16 + l16];
        float s = 0.f;
        #pragma unroll
        for (int f = 0; f < 16; ++f) s += x[f];
        s += __shfl_xor(s, 1); s += __shfl_xor(s, 2);
        s += __shfl_xor(s, 4); s += __shfl_xor(s, 8);
        float mu = s * (1.0f / 256.0f);
        float q = 0.f;
        #pragma unroll
        for (int f = 0; f < 16; ++f) { float d = x[f] - mu; q += d * d; }
        q += __shfl_xor(q, 1); q += __shfl_xor(q, 2);
        q += __shfl_xor(q, 4); q += __shfl_xor(q, 8);
        float rstd = rsqrtf(q * (1.0f / 256.0f) + 1e-5f);
        if (gr < NNODE) {
            #pragma unroll
            for (int f = 0; f < 16; ++f) {
                int col = f * 16 + l16;
                float y = (x[f] - mu) * rstd * loadf(nvg, col, f32) + loadf(nvb, col, f32);
                storef(out, (size_t)gr * HIDD + col, y, f32);
            }
        }
    }
}

extern "C" void kernel_launch(void* const* d_in, const int* in_sizes, int n_in,
                              void* d_out, int out_size, void* d_ws, size_t ws_size,
                              hipStream_t stream)
{
    (void)in_sizes; (void)n_in; (void)out_size; (void)ws_size;
    const void* h   = d_in[0];
    const void* e   = d_in[1];
    const int*  ei  = (const int*)d_in[2];
    const void* We1 = d_in[3];
    const void* be1 = d_in[4];
    const void* We2 = d_in[5];
    const void* be2 = d_in[6];
    const void* Wv1 = d_in[7];
    const void* bv1 = d_in[8];
    const void* Wv2 = d_in[9];
    const void* bv2 = d_in[10];
    const void* neg = d_in[11];
    const void* neb = d_in[12];
    const void* nvg = d_in[13];
    const void* nvb = d_in[14];

    char* ws = (char*)d_ws;
    u32*   flags = (u32*)ws;
    float* S     = (float*)(ws + 256);
    u32*   cnt   = (u32*)(ws + 256 + (size_t)NNODE * HIDD * 4);
    size_t off = 256 + (size_t)NNODE * HIDD * 4 + ((size_t)NNODE * 4 + 255) / 256 * 256;
    int*   head = (int*)(ws + off);            off += ((size_t)NNODE * 4 + 255) / 256 * 256;
    int*   perm = (int*)(ws + off);            off += (size_t)NEDGE * 4;
    int*   dsts = (int*)(ws + off);            off += (size_t)NEDGE * 4;
    ushort* WT1c = (ushort*)(ws + off);        // [128][128]
    ushort* WT2  = WT1c + 128 * 128;           // [128][128]
    ushort* WvcT = WT2  + 128 * 128;           // [256][128]
    ushort* WTv2 = WvcT + 256 * 128;           // [256][256]
    ushort* WTe  = WTv2 + 256 * 256;           // [256][256]  (Qab weights)
    ushort* WTv  = WTe  + 256 * 256;           // [512][256]  (Pab weights)
    ushort* hb   = WTv  + 512 * 256;           // [10000][256] bf16
    ushort* Qab  = hb   + (size_t)NNODE * HIDD;      // [10000][256] bf16
    ushort* Pab  = Qab  + (size_t)NNODE * 256;       // [10000][512] bf16

    hipMemsetAsync(S, 0, (size_t)NNODE * HIDD * 4 + (size_t)NNODE * 4, stream);
    detect_kernel<<<1, 64, 0, stream>>>((const u32*)h, (const u32*)ei, flags);

    // weight transposes (bf16, n-major)
    wt_kernel<<<256, 128, 0, stream>>>(We1, WTe,             0,   256, 128, 128, flags);
    wt_kernel<<<256, 128, 0, stream>>>(We1, WTe + 128 * 256, 256, 256, 128, 128, flags);
    wt_kernel<<<128, 128, 0, stream>>>(We1, WT1c,            512, 128, 128, 128, flags);
    wt_kernel<<<128, 128, 0, stream>>>(We2, WT2,             0,   128, 128, 128, flags);
    wt_kernel<<<256, 256, 0, stream>>>(Wv1, WTv,             0,   256, 256, 256, flags);
    wt_kernel<<<256, 256, 0, stream>>>(Wv1, WTv + 256 * 256, 256, 256, 256, 256, flags);
    wt_kernel<<<128, 256, 0, stream>>>(Wv1, WvcT,            512, 128, 256, 256, flags);
    wt_kernel<<<256, 256, 0, stream>>>(Wv2, WTv2,            0,   256, 256, 256, flags);

    hconv_kernel<<<(NNODE * HIDD / 8 + 255) / 256, 256, 0, stream>>>(h, hb, flags);
    count_kernel<<<(NEDGE + 255) / 256, 256, 0, stream>>>(ei, cnt, flags);
    scan_kernel<<<1, 256, 0, stream>>>(cnt, head);
    fill_kernel<<<(NEDGE + 255) / 256, 256, 0, stream>>>(ei, head, perm, dsts, flags);

    // node-level projections: Qab = hb@[We1 0:512]^T, Pab = hb@[Wv1 0:512]^T
    qp_kernel<4><<<(NNODE + 63) / 64, 256, 0, stream>>>(hb, WTe, Qab);
    qp_kernel<8><<<(NNODE + 63) / 64, 256, 0, stream>>>(hb, WTv, Pab);

    edge_kernel<<<NEDGE / 64, 256, 0, stream>>>(e, ei, WT1c, be1, WT2, be2, Qab,
                                                neg, neb, d_out, flags);
    node1_kernel<<<NEDGE / 64, 256, 0, stream>>>(d_out, ei, perm, dsts,
                                                 WvcT, bv1, Pab, S, flags);
    hn_gemm_kernel<<<(NNODE + 63) / 64, 256, 0, stream>>>(S, WTv2, bv2, cnt, h,
                                                          nvg, nvb, d_out, flags);
}

// Round 12
// 408.638 us; speedup vs baseline: 1.0568x; 1.0523x over previous
//
#include <hip/hip_runtime.h>
#include <hip/hip_bf16.h>

#define NNODE 10000
#define NEDGE 160000
#define HIDD  256
#define ED    128
#define CAT   640

typedef short bf8 __attribute__((ext_vector_type(8)));
typedef float f4  __attribute__((ext_vector_type(4)));
typedef unsigned int u32;

__device__ __forceinline__ float bf2f(ushort u) {
    return __uint_as_float(((unsigned)u) << 16);
}
__device__ __forceinline__ ushort f2bf(float f) {
    unsigned u = __float_as_uint(f);
    return (ushort)((u + 0x7fffu + ((u >> 16) & 1u)) >> 16);
}
__device__ __forceinline__ float gelu_exact(float x) {
    return 0.5f * x * (1.0f + erff(x * 0.70710678118654752f));
}
__device__ __forceinline__ int clampi(int v) {
    return ((unsigned)v >= (unsigned)NNODE) ? 0 : v;
}
__device__ __forceinline__ int getidx(const int* ei, bool i64, int pos) {
    int v = i64 ? ei[2 * pos] : ei[pos];
    return clampi(v);
}
__device__ __forceinline__ float loadf(const void* p, size_t idx, bool f32) {
    return f32 ? ((const float*)p)[idx] : bf2f(((const ushort*)p)[idx]);
}
__device__ __forceinline__ bf8 load8(const void* p, size_t idx, bool f32) {
    if (f32) {
        const float* fp = (const float*)p + idx;
        f4 lo = *(const f4*)fp, hi = *(const f4*)(fp + 4);
        bf8 r;
        r[0] = (short)f2bf(lo[0]); r[1] = (short)f2bf(lo[1]);
        r[2] = (short)f2bf(lo[2]); r[3] = (short)f2bf(lo[3]);
        r[4] = (short)f2bf(hi[0]); r[5] = (short)f2bf(hi[1]);
        r[6] = (short)f2bf(hi[2]); r[7] = (short)f2bf(hi[3]);
        return r;
    }
    return *(const bf8*)((const ushort*)p + idx);
}
__device__ __forceinline__ void storef(void* p, size_t idx, float v, bool f32) {
    if (f32) ((float*)p)[idx] = v;
    else     ((ushort*)p)[idx] = f2bf(v);
}
__device__ __forceinline__ void fadd_native(float* p, float v) {
    unsafeAtomicAdd(p, v);
}

// ---- runtime dtype detection ----
__global__ void detect_kernel(const u32* __restrict__ h_u32,
                              const u32* __restrict__ ei_u32,
                              u32* __restrict__ flags) {
    if (threadIdx.x == 0 && blockIdx.x == 0) {
        int inwin = 0;
        for (int i = 0; i < 64; ++i) {
            u32 e8 = (h_u32[i] >> 7) & 0xFFu;
            if (e8 >= 100u && e8 <= 150u) ++inwin;
        }
        u32 f32 = (inwin < 40) ? 1u : 0u;
        u32 hi_or = 0;
        for (int j = 0; j < 16; ++j) hi_or |= ei_u32[2 * j + 1];
        u32 i64 = (hi_or == 0u) ? 1u : 0u;
        flags[0] = f32;
        flags[1] = i64;
    }
}

// ---- consolidated weight transposes (job table, one launch) ----
// dest layout (elements from WT base):
//   WTe  @ 0      : [256n][256k]  rows 0:128 = We1[0:256]^T, rows 128:256 = We1[256:512]^T
//   WT1c @ 65536  : [128n][128k]  We1[512:640]^T
//   WT2  @ 81920  : [128n][128k]  We2^T
//   WTv  @ 98304  : [512n][256k]  rows 0:256 = Wv1[0:256]^T, rows 256:512 = Wv1[256:512]^T
//   WvcT @ 229376 : [256n][128k]  Wv1[512:640]^T
//   WTv2 @ 262144 : [256n][256k]  Wv2^T
__global__ void prep_kernel(const void* __restrict__ We1, const void* __restrict__ We2,
                            const void* __restrict__ Wv1, const void* __restrict__ Wv2,
                            ushort* __restrict__ WT, const u32* __restrict__ flags) {
    const bool f32 = flags[0] != 0;
    int idx = blockIdx.x * 256 + threadIdx.x;
    if (idx >= 327680) return;
    const void* W; int base, k0, K, Wld;
    if      (idx <  32768) { W = We1; base = 0;      k0 = 0;   K = 256; Wld = 128; }
    else if (idx <  65536) { W = We1; base = 32768;  k0 = 256; K = 256; Wld = 128; }
    else if (idx <  81920) { W = We1; base = 65536;  k0 = 512; K = 128; Wld = 128; }
    else if (idx <  98304) { W = We2; base = 81920;  k0 = 0;   K = 128; Wld = 128; }
    else if (idx < 163840) { W = Wv1; base = 98304;  k0 = 0;   K = 256; Wld = 256; }
    else if (idx < 229376) { W = Wv1; base = 163840; k0 = 256; K = 256; Wld = 256; }
    else if (idx < 262144) { W = Wv1; base = 229376; k0 = 512; K = 128; Wld = 256; }
    else                   { W = Wv2; base = 262144; k0 = 0;   K = 256; Wld = 256; }
    int local = idx - base;
    int k = local & (K - 1);
    int n = local / K;
    WT[idx] = f2bf(loadf(W, (size_t)(k0 + k) * Wld + n, f32));
}

// ---- h convert to bf16 ----
__global__ void hconv_kernel(const void* __restrict__ h, ushort* __restrict__ hb,
                             const u32* __restrict__ flags) {
    const bool f32 = flags[0] != 0;
    int i = blockIdx.x * 256 + threadIdx.x;
    if (i < NNODE * HIDD / 8)
        *(bf8*)&hb[(size_t)i * 8] = load8(h, (size_t)i * 8, f32);
}

// ---- per-dst edge counts ----
__global__ void count_kernel(const int* __restrict__ ei, u32* __restrict__ cnt,
                             const u32* __restrict__ flags) {
    bool i64 = flags[1] != 0;
    int i = blockIdx.x * 256 + threadIdx.x;
    if (i < NEDGE) atomicAdd(&cnt[getidx(ei, i64, NEDGE + i)], 1u);
}

// ---- exclusive prefix scan over cnt -> head ----
__global__ void scan_kernel(const u32* __restrict__ cnt, int* __restrict__ head) {
    __shared__ u32 part[256];
    __shared__ u32 base[256];
    int t = threadIdx.x;
    u32 s = 0;
    for (int j = 0; j < 40; ++j) {
        int i = t * 40 + j;
        if (i < NNODE) s += cnt[i];
    }
    part[t] = s;
    __syncthreads();
    if (t == 0) {
        u32 run = 0;
        for (int i = 0; i < 256; ++i) { base[i] = run; run += part[i]; }
    }
    __syncthreads();
    u32 run = base[t];
    for (int j = 0; j < 40; ++j) {
        int i = t * 40 + j;
        if (i < NNODE) { head[i] = (int)run; run += cnt[i]; }
    }
}

// ---- bucket fill: perm/dsts sorted by dst ----
__global__ void fill_kernel(const int* __restrict__ ei, int* __restrict__ head,
                            int* __restrict__ perm, int* __restrict__ dsts,
                            const u32* __restrict__ flags) {
    bool i64 = flags[1] != 0;
    int i = blockIdx.x * 256 + threadIdx.x;
    if (i < NEDGE) {
        int d = getidx(ei, i64, NEDGE + i);
        int pos = atomicAdd(&head[d], 1);
        perm[pos] = i;
        dsts[pos] = d;
    }
}

// ---- node-level projections (merged): Qab = hb@WTe^T, Pab = hb@WTv^T ----
template<int NB>
__device__ __forceinline__ void qp_body(const ushort* __restrict__ hb,
                                        const ushort* __restrict__ WT,
                                        ushort* __restrict__ O, int bid) {
    const int tid = threadIdx.x;
    const int wid = tid >> 6, lane = tid & 63;
    const int l16 = lane & 15, lg = lane >> 4;
    const int node0 = bid * 64;
    const int N = NB * 64;
    const int n0 = wid * (NB * 16);

    size_t ra[4];
    #pragma unroll
    for (int ai = 0; ai < 4; ++ai) {
        int row = node0 + ai * 16 + l16;
        ra[ai] = (size_t)(row < NNODE ? row : NNODE - 1) * HIDD;
    }
    int bb[NB];
    #pragma unroll
    for (int bi = 0; bi < NB; ++bi) bb[bi] = (n0 + bi * 16 + l16) * HIDD;

    f4 acc[4][NB] = {};
    for (int kc = 0; kc < 4; ++kc) {
        #pragma unroll
        for (int ks = 0; ks < 2; ++ks) {
            int kk = kc * 64 + ks * 32 + lg * 8;
            bf8 b[NB];
            #pragma unroll
            for (int bi = 0; bi < NB; ++bi) b[bi] = *(const bf8*)&WT[bb[bi] + kk];
            #pragma unroll
            for (int ai = 0; ai < 4; ++ai) {
                bf8 a = *(const bf8*)&hb[ra[ai] + kk];
                #pragma unroll
                for (int bi = 0; bi < NB; ++bi)
                    acc[ai][bi] = __builtin_amdgcn_mfma_f32_16x16x32_bf16(a, b[bi], acc[ai][bi], 0, 0, 0);
            }
        }
    }
    #pragma unroll
    for (int bi = 0; bi < NB; ++bi) {
        int col = n0 + bi * 16 + l16;
        #pragma unroll
        for (int ai = 0; ai < 4; ++ai)
            #pragma unroll
            for (int r = 0; r < 4; ++r) {
                int gr = node0 + ai * 16 + lg * 4 + r;
                if (gr < NNODE) O[(size_t)gr * N + col] = f2bf(acc[ai][bi][r]);
            }
    }
}

#define QPB ((NNODE + 63) / 64)
__global__ __launch_bounds__(256) void qp2_kernel(
    const ushort* __restrict__ hb, const ushort* __restrict__ WTe,
    const ushort* __restrict__ WTv, ushort* __restrict__ Qab,
    ushort* __restrict__ Pab) {
    if (blockIdx.x < QPB) qp_body<4>(hb, WTe, Qab, blockIdx.x);
    else                  qp_body<8>(hb, WTv, Pab, blockIdx.x - QPB);
}

// ============ FUSED edge+node1 (dst-sorted) ============
__global__ __launch_bounds__(256) void fused_kernel(
    const void* __restrict__ e, const int* __restrict__ ei,
    const int* __restrict__ perm, const int* __restrict__ dsts,
    const ushort* __restrict__ WT1c, const void* __restrict__ be1,
    const ushort* __restrict__ WT2, const void* __restrict__ be2,
    const ushort* __restrict__ Qab,
    const void* __restrict__ neg, const void* __restrict__ neb,
    const ushort* __restrict__ WvcT, const void* __restrict__ bv1,
    const ushort* __restrict__ Pab,
    float* __restrict__ S, void* __restrict__ out,
    const u32* __restrict__ flags)
{
    const bool f32 = flags[0] != 0, i64 = flags[1] != 0;
    __shared__ ushort Asm[64 * 72];
    __shared__ ushort Bsm[256 * 72];
    __shared__ ushort Tsm[64 * 136];
    __shared__ int PermS[64], SrcS[64], DstS[64];

    const int tid = threadIdx.x;
    const int wid = tid >> 6, lane = tid & 63;
    const int l16 = lane & 15, lg = lane >> 4;
    const int edge0 = blockIdx.x * 64;
    const int rm = wid * 16;

    if (tid < 64) {
        int eid = perm[edge0 + tid];
        PermS[tid] = eid;
        SrcS[tid] = getidx(ei, i64, eid);
        DstS[tid] = dsts[edge0 + tid];
    }
    __syncthreads();

    // ---------- phase 1: T1 = e @ WT1c^T (K=128) ----------
    f4 acc[8] = {};
    for (int kc = 0; kc < 2; ++kc) {
        __syncthreads();
        #pragma unroll
        for (int half = 0; half < 2; ++half) {
            int slot = tid + half * 256;
            int r = slot >> 3, c8 = (slot & 7) * 8;
            int eid = PermS[r];
            *(bf8*)&Asm[r * 72 + c8] = load8(e, (size_t)eid * ED + kc * 64 + c8, f32);
        }
        #pragma unroll
        for (int it = 0; it < 4; ++it) {
            int slot = tid + it * 256;
            int n = slot >> 3, c8 = (slot & 7) * 8;
            *(bf8*)&Bsm[n * 72 + c8] = *(const bf8*)&WT1c[n * 128 + kc * 64 + c8];
        }
        __syncthreads();
        #pragma unroll
        for (int ks = 0; ks < 2; ++ks) {
            bf8 a = *(const bf8*)&Asm[(rm + l16) * 72 + ks * 32 + lg * 8];
            #pragma unroll
            for (int f = 0; f < 8; ++f) {
                bf8 b = *(const bf8*)&Bsm[(f * 16 + l16) * 72 + ks * 32 + lg * 8];
                acc[f] = __builtin_amdgcn_mfma_f32_16x16x32_bf16(a, b, acc[f], 0, 0, 0);
            }
        }
    }

    // epilogue 1: + be1 + Qa[src] + Qb[dst], gelu -> Tsm
    int sidx[4], didx[4];
    #pragma unroll
    for (int r = 0; r < 4; ++r) {
        int row = rm + lg * 4 + r;
        sidx[r] = SrcS[row];
        didx[r] = DstS[row];
    }
    #pragma unroll
    for (int f = 0; f < 8; ++f) {
        int col = f * 16 + l16;
        float bias = loadf(be1, col, f32);
        #pragma unroll
        for (int r = 0; r < 4; ++r) {
            float val = acc[f][r] + bias
                      + bf2f(Qab[(size_t)sidx[r] * 256 + col])
                      + bf2f(Qab[(size_t)didx[r] * 256 + 128 + col]);
            Tsm[(rm + lg * 4 + r) * 136 + col] = f2bf(gelu_exact(val));
        }
    }

    // ---------- phase 2: T2 = T1 @ WT2^T (K=128) ----------
    f4 acc2[8] = {};
    for (int kc = 0; kc < 2; ++kc) {
        __syncthreads();
        #pragma unroll
        for (int it = 0; it < 4; ++it) {
            int slot = tid + it * 256;
            int n = slot >> 3, c8 = (slot & 7) * 8;
            *(bf8*)&Bsm[n * 72 + c8] = *(const bf8*)&WT2[n * 128 + kc * 64 + c8];
        }
        __syncthreads();
        #pragma unroll
        for (int ks = 0; ks < 2; ++ks) {
            bf8 a = *(const bf8*)&Tsm[(rm + l16) * 136 + kc * 64 + ks * 32 + lg * 8];
            #pragma unroll
            for (int f = 0; f < 8; ++f) {
                bf8 b = *(const bf8*)&Bsm[(f * 16 + l16) * 72 + ks * 32 + lg * 8];
                acc2[f] = __builtin_amdgcn_mfma_f32_16x16x32_bf16(a, b, acc2[f], 0, 0, 0);
            }
        }
    }

    // epilogue 2: + be2 + e residual, LN, write e_new to out + Tsm(bf16)
    float v[8][4];
    #pragma unroll
    for (int f = 0; f < 8; ++f) {
        int col = f * 16 + l16;
        float bias = loadf(be2, col, f32);
        #pragma unroll
        for (int r = 0; r < 4; ++r) {
            int row = rm + lg * 4 + r;
            v[f][r] = acc2[f][r] + bias
                    + loadf(e, (size_t)PermS[row] * ED + col, f32);
        }
    }
    #pragma unroll
    for (int r = 0; r < 4; ++r) {
        float s = 0.f;
        #pragma unroll
        for (int f = 0; f < 8; ++f) s += v[f][r];
        s += __shfl_xor(s, 1); s += __shfl_xor(s, 2);
        s += __shfl_xor(s, 4); s += __shfl_xor(s, 8);
        float mu = s * (1.0f / 128.0f);
        float q = 0.f;
        #pragma unroll
        for (int f = 0; f < 8; ++f) { float d = v[f][r] - mu; q += d * d; }
        q += __shfl_xor(q, 1); q += __shfl_xor(q, 2);
        q += __shfl_xor(q, 4); q += __shfl_xor(q, 8);
        float rstd = rsqrtf(q * (1.0f / 128.0f) + 1e-5f);
        int row = rm + lg * 4 + r;
        int eid = PermS[row];
        #pragma unroll
        for (int f = 0; f < 8; ++f) {
            int col = f * 16 + l16;
            float y = (v[f][r] - mu) * rstd * loadf(neg, col, f32) + loadf(neb, col, f32);
            storef(out, (size_t)NNODE * HIDD + (size_t)eid * ED + col, y, f32);
            Tsm[row * 136 + col] = f2bf(y);
        }
    }

    // ---------- phase 3: U = e_new @ WvcT^T (K=128, N=256) ----------
    f4 accN[4][4] = {};
    for (int kc = 0; kc < 2; ++kc) {
        __syncthreads();
        #pragma unroll
        for (int it = 0; it < 8; ++it) {
            int slot = tid + it * 256;
            int n = slot >> 3, c8 = (slot & 7) * 8;
            *(bf8*)&Bsm[n * 72 + c8] = *(const bf8*)&WvcT[n * 128 + kc * 64 + c8];
        }
        __syncthreads();
        #pragma unroll
        for (int ks = 0; ks < 2; ++ks) {
            bf8 a[4], b[4];
            #pragma unroll
            for (int ai = 0; ai < 4; ++ai)
                a[ai] = *(const bf8*)&Tsm[(ai * 16 + l16) * 136 + kc * 64 + ks * 32 + lg * 8];
            #pragma unroll
            for (int bi = 0; bi < 4; ++bi)
                b[bi] = *(const bf8*)&Bsm[(wid * 64 + bi * 16 + l16) * 72 + ks * 32 + lg * 8];
            #pragma unroll
            for (int ai = 0; ai < 4; ++ai)
                #pragma unroll
                for (int bi = 0; bi < 4; ++bi)
                    accN[ai][bi] = __builtin_amdgcn_mfma_f32_16x16x32_bf16(a[ai], b[bi], accN[ai][bi], 0, 0, 0);
        }
    }

    // epilogue 3: + bv1 + Pa[src] + Pb[dst], gelu, run-merged atomic scatter
    float bias[4];
    #pragma unroll
    for (int bi = 0; bi < 4; ++bi) bias[bi] = loadf(bv1, wid * 64 + bi * 16 + l16, f32);
    #pragma unroll
    for (int ai = 0; ai < 4; ++ai) {
        int p0 = ai * 16 + lg * 4;
        int d0 = DstS[p0 + 0], d1 = DstS[p0 + 1];
        int d2 = DstS[p0 + 2], d3 = DstS[p0 + 3];
        int s0 = SrcS[p0 + 0], s1 = SrcS[p0 + 1];
        int s2 = SrcS[p0 + 2], s3 = SrcS[p0 + 3];
        #pragma unroll
        for (int bi = 0; bi < 4; ++bi) {
            int col = wid * 64 + bi * 16 + l16;
            float v0 = gelu_exact(accN[ai][bi][0] + bias[bi]
                     + bf2f(Pab[(size_t)s0 * 512 + col])
                     + bf2f(Pab[(size_t)d0 * 512 + 256 + col]));
            float v1 = gelu_exact(accN[ai][bi][1] + bias[bi]
                     + bf2f(Pab[(size_t)s1 * 512 + col])
                     + bf2f(Pab[(size_t)d1 * 512 + 256 + col]));
            float v2 = gelu_exact(accN[ai][bi][2] + bias[bi]
                     + bf2f(Pab[(size_t)s2 * 512 + col])
                     + bf2f(Pab[(size_t)d2 * 512 + 256 + col]));
            float v3 = gelu_exact(accN[ai][bi][3] + bias[bi]
                     + bf2f(Pab[(size_t)s3 * 512 + col])
                     + bf2f(Pab[(size_t)d3 * 512 + 256 + col]));
            float s = v0; int d = d0;
            if (d1 == d) s += v1; else { fadd_native(&S[(size_t)d * HIDD + col], s); d = d1; s = v1; }
            if (d2 == d) s += v2; else { fadd_native(&S[(size_t)d * HIDD + col], s); d = d2; s = v2; }
            if (d3 == d) s += v3; else { fadd_native(&S[(size_t)d * HIDD + col], s); d = d3; s = v3; }
            fadd_native(&S[(size_t)d * HIDD + col], s);
        }
    }
}

// ---- node phase 2 + LN: h_new = LN(h + (S@Wv2 + cnt*bv2)/max(cnt,1)) ----
__global__ __launch_bounds__(256) void hn_gemm_kernel(
    const float* __restrict__ S, const ushort* __restrict__ WTv2,
    const void* __restrict__ bv2, const u32* __restrict__ cnt,
    const void* __restrict__ h,
    const void* __restrict__ nvg, const void* __restrict__ nvb,
    void* __restrict__ out, const u32* __restrict__ flags)
{
    const bool f32 = flags[0] != 0;
    constexpr int LDV = 260;
    __shared__ float Vsm[64 * LDV];

    const int tid = threadIdx.x;
    const int wid = tid >> 6, lane = tid & 63;
    const int l16 = lane & 15, lg = lane >> 4;
    const int node0 = blockIdx.x * 64;
    const int n0 = wid * 64;

    size_t ra[4];
    #pragma unroll
    for (int ai = 0; ai < 4; ++ai) {
        int row = node0 + ai * 16 + l16;
        ra[ai] = (size_t)(row < NNODE ? row : NNODE - 1) * HIDD;
    }
    int bb[4];
    #pragma unroll
    for (int bi = 0; bi < 4; ++bi) bb[bi] = (n0 + bi * 16 + l16) * HIDD;

    f4 acc[4][4] = {};
    for (int kc = 0; kc < 4; ++kc) {
        #pragma unroll
        for (int ks = 0; ks < 2; ++ks) {
            int kk = kc * 64 + ks * 32 + lg * 8;
            bf8 b[4];
            #pragma unroll
            for (int bi = 0; bi < 4; ++bi) b[bi] = *(const bf8*)&WTv2[bb[bi] + kk];
            #pragma unroll
            for (int ai = 0; ai < 4; ++ai) {
                bf8 a = load8(S, ra[ai] + kk, true);
                #pragma unroll
                for (int bi = 0; bi < 4; ++bi)
                    acc[ai][bi] = __builtin_amdgcn_mfma_f32_16x16x32_bf16(a, b[bi], acc[ai][bi], 0, 0, 0);
            }
        }
    }

    #pragma unroll
    for (int bi = 0; bi < 4; ++bi) {
        int col = n0 + bi * 16 + l16;
        float b2 = loadf(bv2, col, f32);
        #pragma unroll
        for (int ai = 0; ai < 4; ++ai)
            #pragma unroll
            for (int r = 0; r < 4; ++r) {
                int rowl = ai * 16 + lg * 4 + r;
                int gr = node0 + rowl;
                int grc = gr < NNODE ? gr : NNODE - 1;
                float c = (float)cnt[grc];
                float inv = 1.0f / fmaxf(c, 1.0f);
                float val = (acc[ai][bi][r] + c * b2) * inv
                          + loadf(h, (size_t)grc * HIDD + col, f32);
                Vsm[rowl * LDV + col] = val;
            }
    }
    __syncthreads();

    #pragma unroll
    for (int rr = 0; rr < 4; ++rr) {
        int rowl = wid * 16 + lg * 4 + rr;
        int gr = node0 + rowl;
        float x[16];
        #pragma unroll
        for (int f = 0; f < 16; ++f) x[f] = Vsm[rowl * LDV + f * 16 + l16];
        float s = 0.f;
        #pragma unroll
        for (int f = 0; f < 16; ++f) s += x[f];
        s += __shfl_xor(s, 1); s += __shfl_xor(s, 2);
        s += __shfl_xor(s, 4); s += __shfl_xor(s, 8);
        float mu = s * (1.0f / 256.0f);
        float q = 0.f;
        #pragma unroll
        for (int f = 0; f < 16; ++f) { float d = x[f] - mu; q += d * d; }
        q += __shfl_xor(q, 1); q += __shfl_xor(q, 2);
        q += __shfl_xor(q, 4); q += __shfl_xor(q, 8);
        float rstd = rsqrtf(q * (1.0f / 256.0f) + 1e-5f);
        if (gr < NNODE) {
            #pragma unroll
            for (int f = 0; f < 16; ++f) {
                int col = f * 16 + l16;
                float y = (x[f] - mu) * rstd * loadf(nvg, col, f32) + loadf(nvb, col, f32);
                storef(out, (size_t)gr * HIDD + col, y, f32);
            }
        }
    }
}

extern "C" void kernel_launch(void* const* d_in, const int* in_sizes, int n_in,
                              void* d_out, int out_size, void* d_ws, size_t ws_size,
                              hipStream_t stream)
{
    (void)in_sizes; (void)n_in; (void)out_size; (void)ws_size;
    const void* h   = d_in[0];
    const void* e   = d_in[1];
    const int*  ei  = (const int*)d_in[2];
    const void* We1 = d_in[3];
    const void* be1 = d_in[4];
    const void* We2 = d_in[5];
    const void* be2 = d_in[6];
    const void* Wv1 = d_in[7];
    const void* bv1 = d_in[8];
    const void* Wv2 = d_in[9];
    const void* bv2 = d_in[10];
    const void* neg = d_in[11];
    const void* neb = d_in[12];
    const void* nvg = d_in[13];
    const void* nvb = d_in[14];

    char* ws = (char*)d_ws;
    u32*   flags = (u32*)ws;
    float* S     = (float*)(ws + 256);
    u32*   cnt   = (u32*)(ws + 256 + (size_t)NNODE * HIDD * 4);
    size_t off = 256 + (size_t)NNODE * HIDD * 4 + ((size_t)NNODE * 4 + 255) / 256 * 256;
    int*   head = (int*)(ws + off);            off += ((size_t)NNODE * 4 + 255) / 256 * 256;
    int*   perm = (int*)(ws + off);            off += (size_t)NEDGE * 4;
    int*   dsts = (int*)(ws + off);            off += (size_t)NEDGE * 4;
    ushort* WTb  = (ushort*)(ws + off);        // 327680 elements
    ushort* WTe  = WTb;                        // [256][256]
    ushort* WT1c = WTb + 65536;                // [128][128]
    ushort* WT2  = WTb + 81920;                // [128][128]
    ushort* WTv  = WTb + 98304;                // [512][256]
    ushort* WvcT = WTb + 229376;               // [256][128]
    ushort* WTv2 = WTb + 262144;               // [256][256]
    ushort* hb   = WTb + 327680;                       // [10000][256] bf16
    ushort* Qab  = hb + (size_t)NNODE * HIDD;          // [10000][256] bf16
    ushort* Pab  = Qab + (size_t)NNODE * 256;          // [10000][512] bf16

    hipMemsetAsync(S, 0, (size_t)NNODE * HIDD * 4 + (size_t)NNODE * 4, stream);
    detect_kernel<<<1, 64, 0, stream>>>((const u32*)h, (const u32*)ei, flags);

    prep_kernel<<<1280, 256, 0, stream>>>(We1, We2, Wv1, Wv2, WTb, flags);
    hconv_kernel<<<(NNODE * HIDD / 8 + 255) / 256, 256, 0, stream>>>(h, hb, flags);
    count_kernel<<<(NEDGE + 255) / 256, 256, 0, stream>>>(ei, cnt, flags);
    scan_kernel<<<1, 256, 0, stream>>>(cnt, head);
    fill_kernel<<<(NEDGE + 255) / 256, 256, 0, stream>>>(ei, head, perm, dsts, flags);

    qp2_kernel<<<2 * QPB, 256, 0, stream>>>(hb, WTe, WTv, Qab, Pab);

    fused_kernel<<<NEDGE / 64, 256, 0, stream>>>(e, ei, perm, dsts,
                                                 WT1c, be1, WT2, be2, Qab,
                                                 neg, neb, WvcT, bv1, Pab,
                                                 S, d_out, flags);
    hn_gemm_kernel<<<(NNODE + 63) / 64, 256, 0, stream>>>(S, WTv2, bv2, cnt, h,
                                                          nvg, nvb, d_out, flags);
}

// Round 13
// 369.881 us; speedup vs baseline: 1.1676x; 1.1048x over previous
//
#include <hip/hip_runtime.h>
#include <hip/hip_bf16.h>

#define NNODE 10000
#define NEDGE 160000
#define HIDD  256
#define ED    128
#define CAT   640

typedef short bf8 __attribute__((ext_vector_type(8)));
typedef short bf4 __attribute__((ext_vector_type(4)));
typedef float f4  __attribute__((ext_vector_type(4)));
typedef unsigned int u32;

__device__ __forceinline__ float bf2f(ushort u) {
    return __uint_as_float(((unsigned)u) << 16);
}
__device__ __forceinline__ ushort f2bf(float f) {
    unsigned u = __float_as_uint(f);
    return (ushort)((u + 0x7fffu + ((u >> 16) & 1u)) >> 16);
}
__device__ __forceinline__ float gelu_exact(float x) {
    return 0.5f * x * (1.0f + erff(x * 0.70710678118654752f));
}
__device__ __forceinline__ int clampi(int v) {
    return ((unsigned)v >= (unsigned)NNODE) ? 0 : v;
}
__device__ __forceinline__ int getidx(const int* ei, bool i64, int pos) {
    int v = i64 ? ei[2 * pos] : ei[pos];
    return clampi(v);
}
__device__ __forceinline__ float loadf(const void* p, size_t idx, bool f32) {
    return f32 ? ((const float*)p)[idx] : bf2f(((const ushort*)p)[idx]);
}
__device__ __forceinline__ bf8 load8(const void* p, size_t idx, bool f32) {
    if (f32) {
        const float* fp = (const float*)p + idx;
        f4 lo = *(const f4*)fp, hi = *(const f4*)(fp + 4);
        bf8 r;
        r[0] = (short)f2bf(lo[0]); r[1] = (short)f2bf(lo[1]);
        r[2] = (short)f2bf(lo[2]); r[3] = (short)f2bf(lo[3]);
        r[4] = (short)f2bf(hi[0]); r[5] = (short)f2bf(hi[1]);
        r[6] = (short)f2bf(hi[2]); r[7] = (short)f2bf(hi[3]);
        return r;
    }
    return *(const bf8*)((const ushort*)p + idx);
}
__device__ __forceinline__ void storef(void* p, size_t idx, float v, bool f32) {
    if (f32) ((float*)p)[idx] = v;
    else     ((ushort*)p)[idx] = f2bf(v);
}
__device__ __forceinline__ void fadd_native(float* p, float v) {
    unsafeAtomicAdd(p, v);
}

// ---- runtime dtype detection (wave-parallel) ----
__global__ void detect_kernel(const u32* __restrict__ h_u32,
                              const u32* __restrict__ ei_u32,
                              u32* __restrict__ flags) {
    int t = threadIdx.x;            // 64 threads, one wave
    u32 e8 = (h_u32[t] >> 7) & 0xFFu;
    bool inw = (e8 >= 100u && e8 <= 150u);
    unsigned long long m = __ballot(inw);
    bool hi_nz = (t < 16) ? (ei_u32[2 * t + 1] != 0u) : false;
    unsigned long long m2 = __ballot(hi_nz);
    if (t == 0) {
        flags[0] = (__popcll(m) < 40) ? 1u : 0u;   // f32 input?
        flags[1] = (m2 == 0ull) ? 1u : 0u;         // int64 indices?
    }
}

// ---- consolidated weight transposes (job table, one launch) ----
// dest layout (elements from WT base):
//   WTe  @ 0      : [256n][256k]  rows 0:128 = We1[0:256]^T, rows 128:256 = We1[256:512]^T
//   WT1c @ 65536  : [128n][128k]  We1[512:640]^T
//   WT2  @ 81920  : [128n][128k]  We2^T
//   WTv  @ 98304  : [512n][256k]  rows 0:256 = Wv1[0:256]^T, rows 256:512 = Wv1[256:512]^T
//   WvcT @ 229376 : [256n][128k]  Wv1[512:640]^T
//   WTv2 @ 262144 : [256n][256k]  Wv2^T
__global__ void prep_kernel(const void* __restrict__ We1, const void* __restrict__ We2,
                            const void* __restrict__ Wv1, const void* __restrict__ Wv2,
                            ushort* __restrict__ WT, const u32* __restrict__ flags) {
    const bool f32 = flags[0] != 0;
    int idx = blockIdx.x * 256 + threadIdx.x;
    if (idx >= 327680) return;
    const void* W; int base, k0, K, Wld;
    if      (idx <  32768) { W = We1; base = 0;      k0 = 0;   K = 256; Wld = 128; }
    else if (idx <  65536) { W = We1; base = 32768;  k0 = 256; K = 256; Wld = 128; }
    else if (idx <  81920) { W = We1; base = 65536;  k0 = 512; K = 128; Wld = 128; }
    else if (idx <  98304) { W = We2; base = 81920;  k0 = 0;   K = 128; Wld = 128; }
    else if (idx < 163840) { W = Wv1; base = 98304;  k0 = 0;   K = 256; Wld = 256; }
    else if (idx < 229376) { W = Wv1; base = 163840; k0 = 256; K = 256; Wld = 256; }
    else if (idx < 262144) { W = Wv1; base = 229376; k0 = 512; K = 128; Wld = 256; }
    else                   { W = Wv2; base = 262144; k0 = 0;   K = 256; Wld = 256; }
    int local = idx - base;
    int k = local & (K - 1);
    int n = local / K;
    WT[idx] = f2bf(loadf(W, (size_t)(k0 + k) * Wld + n, f32));
}

// ---- h convert to bf16 ----
__global__ void hconv_kernel(const void* __restrict__ h, ushort* __restrict__ hb,
                             const u32* __restrict__ flags) {
    const bool f32 = flags[0] != 0;
    int i = blockIdx.x * 256 + threadIdx.x;
    if (i < NNODE * HIDD / 8)
        *(bf8*)&hb[(size_t)i * 8] = load8(h, (size_t)i * 8, f32);
}

// ---- per-dst edge counts ----
__global__ void count_kernel(const int* __restrict__ ei, u32* __restrict__ cnt,
                             const u32* __restrict__ flags) {
    bool i64 = flags[1] != 0;
    int i = blockIdx.x * 256 + threadIdx.x;
    if (i < NEDGE) atomicAdd(&cnt[getidx(ei, i64, NEDGE + i)], 1u);
}

// ---- exclusive prefix scan over cnt -> head ----
__global__ void scan_kernel(const u32* __restrict__ cnt, int* __restrict__ head) {
    __shared__ u32 part[256];
    __shared__ u32 base[256];
    int t = threadIdx.x;
    u32 s = 0;
    for (int j = 0; j < 40; ++j) {
        int i = t * 40 + j;
        if (i < NNODE) s += cnt[i];
    }
    part[t] = s;
    __syncthreads();
    if (t == 0) {
        u32 run = 0;
        for (int i = 0; i < 256; ++i) { base[i] = run; run += part[i]; }
    }
    __syncthreads();
    u32 run = base[t];
    for (int j = 0; j < 40; ++j) {
        int i = t * 40 + j;
        if (i < NNODE) { head[i] = (int)run; run += cnt[i]; }
    }
}

// ---- bucket fill: perm/dsts sorted by dst ----
__global__ void fill_kernel(const int* __restrict__ ei, int* __restrict__ head,
                            int* __restrict__ perm, int* __restrict__ dsts,
                            const u32* __restrict__ flags) {
    bool i64 = flags[1] != 0;
    int i = blockIdx.x * 256 + threadIdx.x;
    if (i < NEDGE) {
        int d = getidx(ei, i64, NEDGE + i);
        int pos = atomicAdd(&head[d], 1);
        perm[pos] = i;
        dsts[pos] = d;
    }
}

// ---- node-level projections, PERMUTED store layout + bias folding ----
// Qab (NB=4, N=256):  half h=col>>7, c=col&127 -> pcol = h*128 + (c&15)*8 + (c>>4)
//   consumer: lane l16 reads bf8 at [node*256 + h*128 + l16*8], elem f = orig col f*16+l16
//   be1 folded into src half (h==0).
// Pab (NB=8, N=512):  half h=col>>8, c=col&255; nh=c>>7, rem=c&127, w=rem>>5,
//   b2=(rem>>4)&1, l=c&15 -> pcol = h*256 + w*64 + l*4 + nh*2 + b2
//   consumer: lane l16 of wave w reads bf4 at [node*512 + h*256 + w*64 + l16*4],
//   elem (nh*2+bi) = orig col nh*128 + w*32 + bi*16 + l16.  bv1 folded into src half.
template<int NB>
__device__ __forceinline__ void qp_body(const ushort* __restrict__ hb,
                                        const ushort* __restrict__ WT,
                                        const void* __restrict__ bias,
                                        ushort* __restrict__ O, int bid, bool f32) {
    const int tid = threadIdx.x;
    const int wid = tid >> 6, lane = tid & 63;
    const int l16 = lane & 15, lg = lane >> 4;
    const int node0 = bid * 64;
    const int N = NB * 64;
    const int n0 = wid * (NB * 16);

    size_t ra[4];
    #pragma unroll
    for (int ai = 0; ai < 4; ++ai) {
        int row = node0 + ai * 16 + l16;
        ra[ai] = (size_t)(row < NNODE ? row : NNODE - 1) * HIDD;
    }
    int bb[NB];
    #pragma unroll
    for (int bi = 0; bi < NB; ++bi) bb[bi] = (n0 + bi * 16 + l16) * HIDD;

    f4 acc[4][NB] = {};
    for (int kc = 0; kc < 4; ++kc) {
        #pragma unroll
        for (int ks = 0; ks < 2; ++ks) {
            int kk = kc * 64 + ks * 32 + lg * 8;
            bf8 b[NB];
            #pragma unroll
            for (int bi = 0; bi < NB; ++bi) b[bi] = *(const bf8*)&WT[bb[bi] + kk];
            #pragma unroll
            for (int ai = 0; ai < 4; ++ai) {
                bf8 a = *(const bf8*)&hb[ra[ai] + kk];
                #pragma unroll
                for (int bi = 0; bi < NB; ++bi)
                    acc[ai][bi] = __builtin_amdgcn_mfma_f32_16x16x32_bf16(a, b[bi], acc[ai][bi], 0, 0, 0);
            }
        }
    }
    #pragma unroll
    for (int bi = 0; bi < NB; ++bi) {
        int col = n0 + bi * 16 + l16;
        int pcol; float badd;
        if constexpr (NB == 4) {
            int hh = col >> 7, c = col & 127;
            badd = (hh == 0) ? loadf(bias, c, f32) : 0.f;
            pcol = hh * 128 + (c & 15) * 8 + (c >> 4);
        } else {
            int hh = col >> 8, c = col & 255;
            badd = (hh == 0) ? loadf(bias, c, f32) : 0.f;
            int nh2 = c >> 7, rem = c & 127, w = rem >> 5, b2 = (rem >> 4) & 1, l = c & 15;
            pcol = hh * 256 + w * 64 + l * 4 + nh2 * 2 + b2;
        }
        #pragma unroll
        for (int ai = 0; ai < 4; ++ai)
            #pragma unroll
            for (int r = 0; r < 4; ++r) {
                int gr = node0 + ai * 16 + lg * 4 + r;
                if (gr < NNODE) O[(size_t)gr * N + pcol] = f2bf(acc[ai][bi][r] + badd);
            }
    }
}

#define QPB ((NNODE + 63) / 64)
__global__ __launch_bounds__(256) void qp2_kernel(
    const ushort* __restrict__ hb, const ushort* __restrict__ WTe,
    const ushort* __restrict__ WTv, const void* __restrict__ be1,
    const void* __restrict__ bv1, ushort* __restrict__ Qab,
    ushort* __restrict__ Pab, const u32* __restrict__ flags) {
    const bool f32 = flags[0] != 0;
    if (blockIdx.x < QPB) qp_body<4>(hb, WTe, be1, Qab, blockIdx.x, f32);
    else                  qp_body<8>(hb, WTv, bv1, Pab, blockIdx.x - QPB, f32);
}

// ============ FUSED edge+node1 (dst-sorted) ============
__global__ __launch_bounds__(256) void fused_kernel(
    const void* __restrict__ e, const int* __restrict__ ei,
    const int* __restrict__ perm, const int* __restrict__ dsts,
    const ushort* __restrict__ WT1c,
    const ushort* __restrict__ WT2, const void* __restrict__ be2,
    const ushort* __restrict__ Qab,
    const void* __restrict__ neg, const void* __restrict__ neb,
    const ushort* __restrict__ WvcT,
    const ushort* __restrict__ Pab,
    float* __restrict__ S, void* __restrict__ out,
    const u32* __restrict__ flags)
{
    const bool f32 = flags[0] != 0, i64 = flags[1] != 0;
    __shared__ ushort Asm[64 * 72];     // 9216 B
    __shared__ ushort Bsm[128 * 72];    // 18432 B
    __shared__ ushort Tsm[64 * 136];    // 17408 B
    __shared__ int PermS[64], SrcS[64], DstS[64];   // 768 B  -> total 45824 B

    const int tid = threadIdx.x;
    const int wid = tid >> 6, lane = tid & 63;
    const int l16 = lane & 15, lg = lane >> 4;
    const int edge0 = blockIdx.x * 64;
    const int rm = wid * 16;

    if (tid < 64) {
        int eid = perm[edge0 + tid];
        PermS[tid] = eid;
        SrcS[tid] = getidx(ei, i64, eid);
        DstS[tid] = dsts[edge0 + tid];
    }
    __syncthreads();

    // ---------- phase 1: T1 = e @ WT1c^T (K=128) ----------
    f4 acc[8] = {};
    for (int kc = 0; kc < 2; ++kc) {
        __syncthreads();
        #pragma unroll
        for (int half = 0; half < 2; ++half) {
            int slot = tid + half * 256;
            int r = slot >> 3, c8 = (slot & 7) * 8;
            int eid = PermS[r];
            *(bf8*)&Asm[r * 72 + c8] = load8(e, (size_t)eid * ED + kc * 64 + c8, f32);
        }
        #pragma unroll
        for (int it = 0; it < 4; ++it) {
            int slot = tid + it * 256;
            int n = slot >> 3, c8 = (slot & 7) * 8;
            *(bf8*)&Bsm[n * 72 + c8] = *(const bf8*)&WT1c[n * 128 + kc * 64 + c8];
        }
        __syncthreads();
        #pragma unroll
        for (int ks = 0; ks < 2; ++ks) {
            bf8 a = *(const bf8*)&Asm[(rm + l16) * 72 + ks * 32 + lg * 8];
            #pragma unroll
            for (int f = 0; f < 8; ++f) {
                bf8 b = *(const bf8*)&Bsm[(f * 16 + l16) * 72 + ks * 32 + lg * 8];
                acc[f] = __builtin_amdgcn_mfma_f32_16x16x32_bf16(a, b, acc[f], 0, 0, 0);
            }
        }
    }

    // epilogue 1: + (be1 folded in Qab) + Qa[src] + Qb[dst], gelu -> Tsm
    int sidx[4], didx[4];
    #pragma unroll
    for (int r = 0; r < 4; ++r) {
        int row = rm + lg * 4 + r;
        sidx[r] = SrcS[row];
        didx[r] = DstS[row];
    }
    bf8 qs[4], qd[4];
    #pragma unroll
    for (int r = 0; r < 4; ++r) {
        qs[r] = *(const bf8*)&Qab[(size_t)sidx[r] * 256 + l16 * 8];
        qd[r] = *(const bf8*)&Qab[(size_t)didx[r] * 256 + 128 + l16 * 8];
    }
    #pragma unroll
    for (int f = 0; f < 8; ++f) {
        #pragma unroll
        for (int r = 0; r < 4; ++r) {
            float val = acc[f][r] + bf2f((ushort)qs[r][f]) + bf2f((ushort)qd[r][f]);
            Tsm[(rm + lg * 4 + r) * 136 + f * 16 + l16] = f2bf(gelu_exact(val));
        }
    }

    // ---------- phase 2: T2 = T1 @ WT2^T (K=128) ----------
    f4 acc2[8] = {};
    for (int kc = 0; kc < 2; ++kc) {
        __syncthreads();
        #pragma unroll
        for (int it = 0; it < 4; ++it) {
            int slot = tid + it * 256;
            int n = slot >> 3, c8 = (slot & 7) * 8;
            *(bf8*)&Bsm[n * 72 + c8] = *(const bf8*)&WT2[n * 128 + kc * 64 + c8];
        }
        __syncthreads();
        #pragma unroll
        for (int ks = 0; ks < 2; ++ks) {
            bf8 a = *(const bf8*)&Tsm[(rm + l16) * 136 + kc * 64 + ks * 32 + lg * 8];
            #pragma unroll
            for (int f = 0; f < 8; ++f) {
                bf8 b = *(const bf8*)&Bsm[(f * 16 + l16) * 72 + ks * 32 + lg * 8];
                acc2[f] = __builtin_amdgcn_mfma_f32_16x16x32_bf16(a, b, acc2[f], 0, 0, 0);
            }
        }
    }

    // epilogue 2: + be2 + e residual, LN, write e_new to out + Tsm(bf16)
    float v[8][4];
    #pragma unroll
    for (int f = 0; f < 8; ++f) {
        int col = f * 16 + l16;
        float bias = loadf(be2, col, f32);
        #pragma unroll
        for (int r = 0; r < 4; ++r) {
            int row = rm + lg * 4 + r;
            v[f][r] = acc2[f][r] + bias
                    + loadf(e, (size_t)PermS[row] * ED + col, f32);
        }
    }
    #pragma unroll
    for (int r = 0; r < 4; ++r) {
        float s = 0.f;
        #pragma unroll
        for (int f = 0; f < 8; ++f) s += v[f][r];
        s += __shfl_xor(s, 1); s += __shfl_xor(s, 2);
        s += __shfl_xor(s, 4); s += __shfl_xor(s, 8);
        float mu = s * (1.0f / 128.0f);
        float q = 0.f;
        #pragma unroll
        for (int f = 0; f < 8; ++f) { float d = v[f][r] - mu; q += d * d; }
        q += __shfl_xor(q, 1); q += __shfl_xor(q, 2);
        q += __shfl_xor(q, 4); q += __shfl_xor(q, 8);
        float rstd = rsqrtf(q * (1.0f / 128.0f) + 1e-5f);
        int row = rm + lg * 4 + r;
        int eid = PermS[row];
        #pragma unroll
        for (int f = 0; f < 8; ++f) {
            int col = f * 16 + l16;
            float y = (v[f][r] - mu) * rstd * loadf(neg, col, f32) + loadf(neb, col, f32);
            storef(out, (size_t)NNODE * HIDD + (size_t)eid * ED + col, y, f32);
            Tsm[row * 136 + col] = f2bf(y);
        }
    }

    // ---------- phase 3: U = e_new @ WvcT^T (K=128, N=256 in 2 halves) ----------
    f4 accN[4][2][2] = {};   // [ai][nh][bi]
    #pragma unroll
    for (int nh = 0; nh < 2; ++nh) {
        for (int kc = 0; kc < 2; ++kc) {
            __syncthreads();     // first one also publishes Tsm e_new
            #pragma unroll
            for (int it = 0; it < 4; ++it) {
                int slot = tid + it * 256;
                int n = slot >> 3, c8 = (slot & 7) * 8;
                *(bf8*)&Bsm[n * 72 + c8] = *(const bf8*)&WvcT[(nh * 128 + n) * 128 + kc * 64 + c8];
            }
            __syncthreads();
            #pragma unroll
            for (int ks = 0; ks < 2; ++ks) {
                bf8 a[4], b[2];
                #pragma unroll
                for (int ai = 0; ai < 4; ++ai)
                    a[ai] = *(const bf8*)&Tsm[(ai * 16 + l16) * 136 + kc * 64 + ks * 32 + lg * 8];
                #pragma unroll
                for (int bi = 0; bi < 2; ++bi)
                    b[bi] = *(const bf8*)&Bsm[(wid * 32 + bi * 16 + l16) * 72 + ks * 32 + lg * 8];
                #pragma unroll
                for (int ai = 0; ai < 4; ++ai)
                    #pragma unroll
                    for (int bi = 0; bi < 2; ++bi)
                        accN[ai][nh][bi] = __builtin_amdgcn_mfma_f32_16x16x32_bf16(a[ai], b[bi], accN[ai][nh][bi], 0, 0, 0);
            }
        }
    }

    // epilogue 3: + (bv1 folded in Pab) + Pa[src] + Pb[dst], gelu, merged scatter
    #pragma unroll
    for (int ai = 0; ai < 4; ++ai) {
        int p0 = ai * 16 + lg * 4;
        int dd[4], ss[4];
        #pragma unroll
        for (int r = 0; r < 4; ++r) { dd[r] = DstS[p0 + r]; ss[r] = SrcS[p0 + r]; }
        bf4 ps[4], pd[4];
        #pragma unroll
        for (int r = 0; r < 4; ++r) {
            ps[r] = *(const bf4*)&Pab[(size_t)ss[r] * 512 + wid * 64 + l16 * 4];
            pd[r] = *(const bf4*)&Pab[(size_t)dd[r] * 512 + 256 + wid * 64 + l16 * 4];
        }
        #pragma unroll
        for (int nh = 0; nh < 2; ++nh)
            #pragma unroll
            for (int bi = 0; bi < 2; ++bi) {
                int col = nh * 128 + wid * 32 + bi * 16 + l16;
                const int j = nh * 2 + bi;
                float v0 = gelu_exact(accN[ai][nh][bi][0] + bf2f((ushort)ps[0][j]) + bf2f((ushort)pd[0][j]));
                float v1 = gelu_exact(accN[ai][nh][bi][1] + bf2f((ushort)ps[1][j]) + bf2f((ushort)pd[1][j]));
                float v2 = gelu_exact(accN[ai][nh][bi][2] + bf2f((ushort)ps[2][j]) + bf2f((ushort)pd[2][j]));
                float v3 = gelu_exact(accN[ai][nh][bi][3] + bf2f((ushort)ps[3][j]) + bf2f((ushort)pd[3][j]));
                float s = v0; int d = dd[0];
                if (dd[1] == d) s += v1; else { fadd_native(&S[(size_t)d * HIDD + col], s); d = dd[1]; s = v1; }
                if (dd[2] == d) s += v2; else { fadd_native(&S[(size_t)d * HIDD + col], s); d = dd[2]; s = v2; }
                if (dd[3] == d) s += v3; else { fadd_native(&S[(size_t)d * HIDD + col], s); d = dd[3]; s = v3; }
                fadd_native(&S[(size_t)d * HIDD + col], s);
            }
    }
}

// ---- node phase 2 + LN: h_new = LN(h + (S@Wv2 + cnt*bv2)/max(cnt,1)) ----
__global__ __launch_bounds__(256) void hn_gemm_kernel(
    const float* __restrict__ S, const ushort* __restrict__ WTv2,
    const void* __restrict__ bv2, const u32* __restrict__ cnt,
    const void* __restrict__ h,
    const void* __restrict__ nvg, const void* __restrict__ nvb,
    void* __restrict__ out, const u32* __restrict__ flags)
{
    const bool f32 = flags[0] != 0;
    constexpr int LDV = 260;
    __shared__ float Vsm[64 * LDV];

    const int tid = threadIdx.x;
    const int wid = tid >> 6, lane = tid & 63;
    const int l16 = lane & 15, lg = lane >> 4;
    const int node0 = blockIdx.x * 64;
    const int n0 = wid * 64;

    size_t ra[4];
    #pragma unroll
    for (int ai = 0; ai < 4; ++ai) {
        int row = node0 + ai * 16 + l16;
        ra[ai] = (size_t)(row < NNODE ? row : NNODE - 1) * HIDD;
    }
    int bb[4];
    #pragma unroll
    for (int bi = 0; bi < 4; ++bi) bb[bi] = (n0 + bi * 16 + l16) * HIDD;

    f4 acc[4][4] = {};
    for (int kc = 0; kc < 4; ++kc) {
        #pragma unroll
        for (int ks = 0; ks < 2; ++ks) {
            int kk = kc * 64 + ks * 32 + lg * 8;
            bf8 b[4];
            #pragma unroll
            for (int bi = 0; bi < 4; ++bi) b[bi] = *(const bf8*)&WTv2[bb[bi] + kk];
            #pragma unroll
            for (int ai = 0; ai < 4; ++ai) {
                bf8 a = load8(S, ra[ai] + kk, true);
                #pragma unroll
                for (int bi = 0; bi < 4; ++bi)
                    acc[ai][bi] = __builtin_amdgcn_mfma_f32_16x16x32_bf16(a, b[bi], acc[ai][bi], 0, 0, 0);
            }
        }
    }

    #pragma unroll
    for (int bi = 0; bi < 4; ++bi) {
        int col = n0 + bi * 16 + l16;
        float b2 = loadf(bv2, col, f32);
        #pragma unroll
        for (int ai = 0; ai < 4; ++ai)
            #pragma unroll
            for (int r = 0; r < 4; ++r) {
                int rowl = ai * 16 + lg * 4 + r;
                int gr = node0 + rowl;
                int grc = gr < NNODE ? gr : NNODE - 1;
                float c = (float)cnt[grc];
                float inv = 1.0f / fmaxf(c, 1.0f);
                float val = (acc[ai][bi][r] + c * b2) * inv
                          + loadf(h, (size_t)grc * HIDD + col, f32);
                Vsm[rowl * LDV + col] = val;
            }
    }
    __syncthreads();

    #pragma unroll
    for (int rr = 0; rr < 4; ++rr) {
        int rowl = wid * 16 + lg * 4 + rr;
        int gr = node0 + rowl;
        float x[16];
        #pragma unroll
        for (int f = 0; f < 16; ++f) x[f] = Vsm[rowl * LDV + f * 16 + l16];
        float s = 0.f;
        #pragma unroll
        for (int f = 0; f < 16; ++f) s += x[f];
        s += __shfl_xor(s, 1); s += __shfl_xor(s, 2);
        s += __shfl_xor(s, 4); s += __shfl_xor(s, 8);
        float mu = s * (1.0f / 256.0f);
        float q = 0.f;
        #pragma unroll
        for (int f = 0; f < 16; ++f) { float d = x[f] - mu; q += d * d; }
        q += __shfl_xor(q, 1); q += __shfl_xor(q, 2);
        q += __shfl_xor(q, 4); q += __shfl_xor(q, 8);
        float rstd = rsqrtf(q * (1.0f / 256.0f) + 1e-5f);
        if (gr < NNODE) {
            #pragma unroll
            for (int f = 0; f < 16; ++f) {
                int col = f * 16 + l16;
                float y = (x[f] - mu) * rstd * loadf(nvg, col, f32) + loadf(nvb, col, f32);
                storef(out, (size_t)gr * HIDD + col, y, f32);
            }
        }
    }
}

extern "C" void kernel_launch(void* const* d_in, const int* in_sizes, int n_in,
                              void* d_out, int out_size, void* d_ws, size_t ws_size,
                              hipStream_t stream)
{
    (void)in_sizes; (void)n_in; (void)out_size; (void)ws_size;
    const void* h   = d_in[0];
    const void* e   = d_in[1];
    const int*  ei  = (const int*)d_in[2];
    const void* We1 = d_in[3];
    const void* be1 = d_in[4];
    const void* We2 = d_in[5];
    const void* be2 = d_in[6];
    const void* Wv1 = d_in[7];
    const void* bv1 = d_in[8];
    const void* Wv2 = d_in[9];
    const void* bv2 = d_in[10];
    const void* neg = d_in[11];
    const void* neb = d_in[12];
    const void* nvg = d_in[13];
    const void* nvb = d_in[14];

    char* ws = (char*)d_ws;
    u32*   flags = (u32*)ws;
    float* S     = (float*)(ws + 256);
    u32*   cnt   = (u32*)(ws + 256 + (size_t)NNODE * HIDD * 4);
    size_t off = 256 + (size_t)NNODE * HIDD * 4 + ((size_t)NNODE * 4 + 255) / 256 * 256;
    int*   head = (int*)(ws + off);            off += ((size_t)NNODE * 4 + 255) / 256 * 256;
    int*   perm = (int*)(ws + off);            off += (size_t)NEDGE * 4;
    int*   dsts = (int*)(ws + off);            off += (size_t)NEDGE * 4;
    ushort* WTb  = (ushort*)(ws + off);        // 327680 elements
    ushort* WTe  = WTb;                        // [256][256]
    ushort* WT1c = WTb + 65536;                // [128][128]
    ushort* WT2  = WTb + 81920;                // [128][128]
    ushort* WTv  = WTb + 98304;                // [512][256]
    ushort* WvcT = WTb + 229376;               // [256][128]
    ushort* WTv2 = WTb + 262144;               // [256][256]
    ushort* hb   = WTb + 327680;                       // [10000][256] bf16
    ushort* Qab  = hb + (size_t)NNODE * HIDD;          // [10000][256] bf16 (permuted)
    ushort* Pab  = Qab + (size_t)NNODE * 256;          // [10000][512] bf16 (permuted)

    hipMemsetAsync(S, 0, (size_t)NNODE * HIDD * 4 + (size_t)NNODE * 4, stream);
    detect_kernel<<<1, 64, 0, stream>>>((const u32*)h, (const u32*)ei, flags);

    prep_kernel<<<1280, 256, 0, stream>>>(We1, We2, Wv1, Wv2, WTb, flags);
    hconv_kernel<<<(NNODE * HIDD / 8 + 255) / 256, 256, 0, stream>>>(h, hb, flags);
    count_kernel<<<(NEDGE + 255) / 256, 256, 0, stream>>>(ei, cnt, flags);
    scan_kernel<<<1, 256, 0, stream>>>(cnt, head);
    fill_kernel<<<(NEDGE + 255) / 256, 256, 0, stream>>>(ei, head, perm, dsts, flags);

    qp2_kernel<<<2 * QPB, 256, 0, stream>>>(hb, WTe, WTv, be1, bv1, Qab, Pab, flags);

    fused_kernel<<<NEDGE / 64, 256, 0, stream>>>(e, ei, perm, dsts,
                                                 WT1c, WT2, be2, Qab,
                                                 neg, neb, WvcT, Pab,
                                                 S, d_out, flags);
    hn_gemm_kernel<<<(NNODE + 63) / 64, 256, 0, stream>>>(S, WTv2, bv2, cnt, h,
                                                          nvg, nvb, d_out, flags);
}

// Round 14
// 361.698 us; speedup vs baseline: 1.1940x; 1.0226x over previous
//
#include <hip/hip_runtime.h>
#include <hip/hip_bf16.h>

#define NNODE 10000
#define NEDGE 160000
#define HIDD  256
#define ED    128
#define CAT   640

typedef short bf8 __attribute__((ext_vector_type(8)));
typedef short bf4 __attribute__((ext_vector_type(4)));
typedef float f4  __attribute__((ext_vector_type(4)));
typedef unsigned int u32;

__device__ __forceinline__ float bf2f(ushort u) {
    return __uint_as_float(((unsigned)u) << 16);
}
__device__ __forceinline__ ushort f2bf(float f) {
    unsigned u = __float_as_uint(f);
    return (ushort)((u + 0x7fffu + ((u >> 16) & 1u)) >> 16);
}
// fast tanh-form gelu (max |err| vs exact ~3e-3, amortizes to <0.02 post-GEMM)
__device__ __forceinline__ float gelu_fast(float x) {
    float x2 = x * x;
    float u = 0.7978845608028654f * x * (1.0f + 0.044715f * x2);
    float au = fabsf(u);
    float ex = __expf(2.0f * au);
    float t = 1.0f - 2.0f / (1.0f + ex);
    t = copysignf(t, u);
    return 0.5f * x * (1.0f + t);
}
__device__ __forceinline__ int clampi(int v) {
    return ((unsigned)v >= (unsigned)NNODE) ? 0 : v;
}
__device__ __forceinline__ int getidx(const int* ei, bool i64, int pos) {
    int v = i64 ? ei[2 * pos] : ei[pos];
    return clampi(v);
}
__device__ __forceinline__ float loadf(const void* p, size_t idx, bool f32) {
    return f32 ? ((const float*)p)[idx] : bf2f(((const ushort*)p)[idx]);
}
__device__ __forceinline__ bf8 load8(const void* p, size_t idx, bool f32) {
    if (f32) {
        const float* fp = (const float*)p + idx;
        f4 lo = *(const f4*)fp, hi = *(const f4*)(fp + 4);
        bf8 r;
        r[0] = (short)f2bf(lo[0]); r[1] = (short)f2bf(lo[1]);
        r[2] = (short)f2bf(lo[2]); r[3] = (short)f2bf(lo[3]);
        r[4] = (short)f2bf(hi[0]); r[5] = (short)f2bf(hi[1]);
        r[6] = (short)f2bf(hi[2]); r[7] = (short)f2bf(hi[3]);
        return r;
    }
    return *(const bf8*)((const ushort*)p + idx);
}
__device__ __forceinline__ void storef(void* p, size_t idx, float v, bool f32) {
    if (f32) ((float*)p)[idx] = v;
    else     ((ushort*)p)[idx] = f2bf(v);
}
__device__ __forceinline__ void fadd_native(float* p, float v) {
    unsafeAtomicAdd(p, v);
}

// ---- runtime dtype detection (wave-parallel) ----
__global__ void detect_kernel(const u32* __restrict__ h_u32,
                              const u32* __restrict__ ei_u32,
                              u32* __restrict__ flags) {
    int t = threadIdx.x;
    u32 e8 = (h_u32[t] >> 7) & 0xFFu;
    bool inw = (e8 >= 100u && e8 <= 150u);
    unsigned long long m = __ballot(inw);
    bool hi_nz = (t < 16) ? (ei_u32[2 * t + 1] != 0u) : false;
    unsigned long long m2 = __ballot(hi_nz);
    if (t == 0) {
        flags[0] = (__popcll(m) < 40) ? 1u : 0u;
        flags[1] = (m2 == 0ull) ? 1u : 0u;
    }
}

// ---- consolidated weight transposes ----
__global__ void prep_kernel(const void* __restrict__ We1, const void* __restrict__ We2,
                            const void* __restrict__ Wv1, const void* __restrict__ Wv2,
                            ushort* __restrict__ WT, const u32* __restrict__ flags) {
    const bool f32 = flags[0] != 0;
    int idx = blockIdx.x * 256 + threadIdx.x;
    if (idx >= 327680) return;
    const void* W; int base, k0, K, Wld;
    if      (idx <  32768) { W = We1; base = 0;      k0 = 0;   K = 256; Wld = 128; }
    else if (idx <  65536) { W = We1; base = 32768;  k0 = 256; K = 256; Wld = 128; }
    else if (idx <  81920) { W = We1; base = 65536;  k0 = 512; K = 128; Wld = 128; }
    else if (idx <  98304) { W = We2; base = 81920;  k0 = 0;   K = 128; Wld = 128; }
    else if (idx < 163840) { W = Wv1; base = 98304;  k0 = 0;   K = 256; Wld = 256; }
    else if (idx < 229376) { W = Wv1; base = 163840; k0 = 256; K = 256; Wld = 256; }
    else if (idx < 262144) { W = Wv1; base = 229376; k0 = 512; K = 128; Wld = 256; }
    else                   { W = Wv2; base = 262144; k0 = 0;   K = 256; Wld = 256; }
    int local = idx - base;
    int k = local & (K - 1);
    int n = local / K;
    WT[idx] = f2bf(loadf(W, (size_t)(k0 + k) * Wld + n, f32));
}

// ---- h convert to bf16 ----
__global__ void hconv_kernel(const void* __restrict__ h, ushort* __restrict__ hb,
                             const u32* __restrict__ flags) {
    const bool f32 = flags[0] != 0;
    int i = blockIdx.x * 256 + threadIdx.x;
    if (i < NNODE * HIDD / 8)
        *(bf8*)&hb[(size_t)i * 8] = load8(h, (size_t)i * 8, f32);
}

// ---- per-dst edge counts ----
__global__ void count_kernel(const int* __restrict__ ei, u32* __restrict__ cnt,
                             const u32* __restrict__ flags) {
    bool i64 = flags[1] != 0;
    int i = blockIdx.x * 256 + threadIdx.x;
    if (i < NEDGE) atomicAdd(&cnt[getidx(ei, i64, NEDGE + i)], 1u);
}

// ---- exclusive prefix scan over cnt -> head ----
__global__ void scan_kernel(const u32* __restrict__ cnt, int* __restrict__ head) {
    __shared__ u32 part[256];
    __shared__ u32 base[256];
    int t = threadIdx.x;
    u32 s = 0;
    for (int j = 0; j < 40; ++j) {
        int i = t * 40 + j;
        if (i < NNODE) s += cnt[i];
    }
    part[t] = s;
    __syncthreads();
    if (t == 0) {
        u32 run = 0;
        for (int i = 0; i < 256; ++i) { base[i] = run; run += part[i]; }
    }
    __syncthreads();
    u32 run = base[t];
    for (int j = 0; j < 40; ++j) {
        int i = t * 40 + j;
        if (i < NNODE) { head[i] = (int)run; run += cnt[i]; }
    }
}

// ---- bucket fill ----
__global__ void fill_kernel(const int* __restrict__ ei, int* __restrict__ head,
                            int* __restrict__ perm, int* __restrict__ dsts,
                            const u32* __restrict__ flags) {
    bool i64 = flags[1] != 0;
    int i = blockIdx.x * 256 + threadIdx.x;
    if (i < NEDGE) {
        int d = getidx(ei, i64, NEDGE + i);
        int pos = atomicAdd(&head[d], 1);
        perm[pos] = i;
        dsts[pos] = d;
    }
}

// ---- node-level projections, permuted layout + bias folding ----
template<int NB>
__device__ __forceinline__ void qp_body(const ushort* __restrict__ hb,
                                        const ushort* __restrict__ WT,
                                        const void* __restrict__ bias,
                                        ushort* __restrict__ O, int bid, bool f32) {
    const int tid = threadIdx.x;
    const int wid = tid >> 6, lane = tid & 63;
    const int l16 = lane & 15, lg = lane >> 4;
    const int node0 = bid * 64;
    const int N = NB * 64;
    const int n0 = wid * (NB * 16);

    size_t ra[4];
    #pragma unroll
    for (int ai = 0; ai < 4; ++ai) {
        int row = node0 + ai * 16 + l16;
        ra[ai] = (size_t)(row < NNODE ? row : NNODE - 1) * HIDD;
    }
    int bb[NB];
    #pragma unroll
    for (int bi = 0; bi < NB; ++bi) bb[bi] = (n0 + bi * 16 + l16) * HIDD;

    f4 acc[4][NB] = {};
    for (int kc = 0; kc < 4; ++kc) {
        #pragma unroll
        for (int ks = 0; ks < 2; ++ks) {
            int kk = kc * 64 + ks * 32 + lg * 8;
            bf8 b[NB];
            #pragma unroll
            for (int bi = 0; bi < NB; ++bi) b[bi] = *(const bf8*)&WT[bb[bi] + kk];
            #pragma unroll
            for (int ai = 0; ai < 4; ++ai) {
                bf8 a = *(const bf8*)&hb[ra[ai] + kk];
                #pragma unroll
                for (int bi = 0; bi < NB; ++bi)
                    acc[ai][bi] = __builtin_amdgcn_mfma_f32_16x16x32_bf16(a, b[bi], acc[ai][bi], 0, 0, 0);
            }
        }
    }
    #pragma unroll
    for (int bi = 0; bi < NB; ++bi) {
        int col = n0 + bi * 16 + l16;
        int pcol; float badd;
        if constexpr (NB == 4) {
            int hh = col >> 7, c = col & 127;
            badd = (hh == 0) ? loadf(bias, c, f32) : 0.f;
            pcol = hh * 128 + (c & 15) * 8 + (c >> 4);
        } else {
            int hh = col >> 8, c = col & 255;
            badd = (hh == 0) ? loadf(bias, c, f32) : 0.f;
            int nh2 = c >> 7, rem = c & 127, w = rem >> 5, b2 = (rem >> 4) & 1, l = c & 15;
            pcol = hh * 256 + w * 64 + l * 4 + nh2 * 2 + b2;
        }
        #pragma unroll
        for (int ai = 0; ai < 4; ++ai)
            #pragma unroll
            for (int r = 0; r < 4; ++r) {
                int gr = node0 + ai * 16 + lg * 4 + r;
                if (gr < NNODE) O[(size_t)gr * N + pcol] = f2bf(acc[ai][bi][r] + badd);
            }
    }
}

#define QPB ((NNODE + 63) / 64)
__global__ __launch_bounds__(256) void qp2_kernel(
    const ushort* __restrict__ hb, const ushort* __restrict__ WTe,
    const ushort* __restrict__ WTv, const void* __restrict__ be1,
    const void* __restrict__ bv1, ushort* __restrict__ Qab,
    ushort* __restrict__ Pab, const u32* __restrict__ flags) {
    const bool f32 = flags[0] != 0;
    if (blockIdx.x < QPB) qp_body<4>(hb, WTe, be1, Qab, blockIdx.x, f32);
    else                  qp_body<8>(hb, WTv, bv1, Pab, blockIdx.x - QPB, f32);
}

// ============ FUSED edge+node1 (dst-sorted), 128 edges/block, 512 thr ============
#define FWG (NEDGE / 128)   // 1250 blocks
__global__ __launch_bounds__(512) void fused_kernel(
    const void* __restrict__ e, const int* __restrict__ ei,
    const int* __restrict__ perm, const int* __restrict__ dsts,
    const ushort* __restrict__ WT1c,
    const ushort* __restrict__ WT2, const void* __restrict__ be2,
    const ushort* __restrict__ Qab,
    const void* __restrict__ neg, const void* __restrict__ neb,
    const ushort* __restrict__ WvcT,
    const ushort* __restrict__ Pab,
    float* __restrict__ S, void* __restrict__ out,
    const u32* __restrict__ flags)
{
    const bool f32 = flags[0] != 0, i64 = flags[1] != 0;
    __shared__ ushort Asm[128 * 72];    // 18432 B
    __shared__ ushort Bsm[128 * 72];    // 18432 B
    __shared__ ushort Tsm[128 * 136];   // 34816 B
    __shared__ int PermS[128], SrcS[128], DstS[128];  // 1536 B -> 73216 B total

    // bijective XCD swizzle (nwg=1250: q=156, r=2)
    int orig = blockIdx.x;
    int xcd = orig & 7, slot = orig >> 3;
    int bid = (xcd < 2 ? xcd * 157 : 2 * 157 + (xcd - 2) * 156) + slot;

    const int tid = threadIdx.x;
    const int wid = tid >> 6, lane = tid & 63;
    const int l16 = lane & 15, lg = lane >> 4;
    const int edge0 = bid * 128;
    const int rm = wid * 16;

    if (tid < 128) {
        int eid = perm[edge0 + tid];
        PermS[tid] = eid;
        SrcS[tid] = getidx(ei, i64, eid);
        DstS[tid] = dsts[edge0 + tid];
    }
    __syncthreads();

    // ---------- phase 1: T1 = e @ WT1c^T (K=128, 128 rows, N=128) ----------
    f4 acc[8] = {};
    for (int kc = 0; kc < 2; ++kc) {
        __syncthreads();
        #pragma unroll
        for (int half = 0; half < 2; ++half) {
            int slot2 = tid + half * 512;
            int r = slot2 >> 3, c8 = (slot2 & 7) * 8;
            int eid = PermS[r];
            *(bf8*)&Asm[r * 72 + c8] = load8(e, (size_t)eid * ED + kc * 64 + c8, f32);
        }
        #pragma unroll
        for (int it = 0; it < 2; ++it) {
            int slot2 = tid + it * 512;
            int n = slot2 >> 3, c8 = (slot2 & 7) * 8;
            *(bf8*)&Bsm[n * 72 + c8] = *(const bf8*)&WT1c[n * 128 + kc * 64 + c8];
        }
        __syncthreads();
        #pragma unroll
        for (int ks = 0; ks < 2; ++ks) {
            bf8 a = *(const bf8*)&Asm[(rm + l16) * 72 + ks * 32 + lg * 8];
            #pragma unroll
            for (int f = 0; f < 8; ++f) {
                bf8 b = *(const bf8*)&Bsm[(f * 16 + l16) * 72 + ks * 32 + lg * 8];
                acc[f] = __builtin_amdgcn_mfma_f32_16x16x32_bf16(a, b, acc[f], 0, 0, 0);
            }
        }
    }

    // epilogue 1: + (be1 in Qab) + Qa[src] + Qb[dst], gelu -> Tsm
    {
        int sidx[4], didx[4];
        #pragma unroll
        for (int r = 0; r < 4; ++r) {
            int row = rm + lg * 4 + r;
            sidx[r] = SrcS[row];
            didx[r] = DstS[row];
        }
        bf8 qs[4], qd[4];
        #pragma unroll
        for (int r = 0; r < 4; ++r) {
            qs[r] = *(const bf8*)&Qab[(size_t)sidx[r] * 256 + l16 * 8];
            qd[r] = *(const bf8*)&Qab[(size_t)didx[r] * 256 + 128 + l16 * 8];
        }
        #pragma unroll
        for (int f = 0; f < 8; ++f) {
            #pragma unroll
            for (int r = 0; r < 4; ++r) {
                float val = acc[f][r] + bf2f((ushort)qs[r][f]) + bf2f((ushort)qd[r][f]);
                Tsm[(rm + lg * 4 + r) * 136 + f * 16 + l16] = f2bf(gelu_fast(val));
            }
        }
    }

    // ---------- phase 2: T2 = T1 @ WT2^T (K=128) ----------
    f4 acc2[8] = {};
    for (int kc = 0; kc < 2; ++kc) {
        __syncthreads();
        #pragma unroll
        for (int it = 0; it < 2; ++it) {
            int slot2 = tid + it * 512;
            int n = slot2 >> 3, c8 = (slot2 & 7) * 8;
            *(bf8*)&Bsm[n * 72 + c8] = *(const bf8*)&WT2[n * 128 + kc * 64 + c8];
        }
        __syncthreads();
        #pragma unroll
        for (int ks = 0; ks < 2; ++ks) {
            bf8 a = *(const bf8*)&Tsm[(rm + l16) * 136 + kc * 64 + ks * 32 + lg * 8];
            #pragma unroll
            for (int f = 0; f < 8; ++f) {
                bf8 b = *(const bf8*)&Bsm[(f * 16 + l16) * 72 + ks * 32 + lg * 8];
                acc2[f] = __builtin_amdgcn_mfma_f32_16x16x32_bf16(a, b, acc2[f], 0, 0, 0);
            }
        }
    }

    // epilogue 2: + be2 + e residual, LN, write e_new to out + Tsm(bf16)
    {
        float v[8][4];
        #pragma unroll
        for (int f = 0; f < 8; ++f) {
            int col = f * 16 + l16;
            float bias = loadf(be2, col, f32);
            #pragma unroll
            for (int r = 0; r < 4; ++r) {
                int row = rm + lg * 4 + r;
                v[f][r] = acc2[f][r] + bias
                        + loadf(e, (size_t)PermS[row] * ED + col, f32);
            }
        }
        #pragma unroll
        for (int r = 0; r < 4; ++r) {
            float s = 0.f;
            #pragma unroll
            for (int f = 0; f < 8; ++f) s += v[f][r];
            s += __shfl_xor(s, 1); s += __shfl_xor(s, 2);
            s += __shfl_xor(s, 4); s += __shfl_xor(s, 8);
            float mu = s * (1.0f / 128.0f);
            float q = 0.f;
            #pragma unroll
            for (int f = 0; f < 8; ++f) { float d = v[f][r] - mu; q += d * d; }
            q += __shfl_xor(q, 1); q += __shfl_xor(q, 2);
            q += __shfl_xor(q, 4); q += __shfl_xor(q, 8);
            float rstd = rsqrtf(q * (1.0f / 128.0f) + 1e-5f);
            int row = rm + lg * 4 + r;
            int eid = PermS[row];
            #pragma unroll
            for (int f = 0; f < 8; ++f) {
                int col = f * 16 + l16;
                float y = (v[f][r] - mu) * rstd * loadf(neg, col, f32) + loadf(neb, col, f32);
                storef(out, (size_t)NNODE * HIDD + (size_t)eid * ED + col, y, f32);
                Tsm[row * 136 + col] = f2bf(y);
            }
        }
    }

    // ---------- phase 3: U = e_new @ WvcT^T (K=128, N=256 in 2 halves) ----------
    const int wr = wid >> 2, wc = wid & 3;
    f4 accN[4][2][2] = {};   // [ai][nh][bi]
    #pragma unroll
    for (int nh = 0; nh < 2; ++nh) {
        for (int kc = 0; kc < 2; ++kc) {
            __syncthreads();     // first also publishes Tsm e_new
            #pragma unroll
            for (int it = 0; it < 2; ++it) {
                int slot2 = tid + it * 512;
                int n = slot2 >> 3, c8 = (slot2 & 7) * 8;
                *(bf8*)&Bsm[n * 72 + c8] = *(const bf8*)&WvcT[(nh * 128 + n) * 128 + kc * 64 + c8];
            }
            __syncthreads();
            #pragma unroll
            for (int ks = 0; ks < 2; ++ks) {
                bf8 a[4], b[2];
                #pragma unroll
                for (int ai = 0; ai < 4; ++ai)
                    a[ai] = *(const bf8*)&Tsm[(wr * 64 + ai * 16 + l16) * 136 + kc * 64 + ks * 32 + lg * 8];
                #pragma unroll
                for (int bi = 0; bi < 2; ++bi)
                    b[bi] = *(const bf8*)&Bsm[(wc * 32 + bi * 16 + l16) * 72 + ks * 32 + lg * 8];
                #pragma unroll
                for (int ai = 0; ai < 4; ++ai)
                    #pragma unroll
                    for (int bi = 0; bi < 2; ++bi)
                        accN[ai][nh][bi] = __builtin_amdgcn_mfma_f32_16x16x32_bf16(a[ai], b[bi], accN[ai][nh][bi], 0, 0, 0);
            }
        }
    }

    // epilogue 3: + (bv1 in Pab) + Pa[src] + Pb[dst], gelu, merged scatter
    #pragma unroll
    for (int ai = 0; ai < 4; ++ai) {
        int p0 = wr * 64 + ai * 16 + lg * 4;
        int dd[4], ss[4];
        #pragma unroll
        for (int r = 0; r < 4; ++r) { dd[r] = DstS[p0 + r]; ss[r] = SrcS[p0 + r]; }
        bf4 ps[4], pd[4];
        #pragma unroll
        for (int r = 0; r < 4; ++r) {
            ps[r] = *(const bf4*)&Pab[(size_t)ss[r] * 512 + wc * 64 + l16 * 4];
            pd[r] = *(const bf4*)&Pab[(size_t)dd[r] * 512 + 256 + wc * 64 + l16 * 4];
        }
        #pragma unroll
        for (int nh = 0; nh < 2; ++nh)
            #pragma unroll
            for (int bi = 0; bi < 2; ++bi) {
                int col = nh * 128 + wc * 32 + bi * 16 + l16;
                const int j = nh * 2 + bi;
                float v0 = gelu_fast(accN[ai][nh][bi][0] + bf2f((ushort)ps[0][j]) + bf2f((ushort)pd[0][j]));
                float v1 = gelu_fast(accN[ai][nh][bi][1] + bf2f((ushort)ps[1][j]) + bf2f((ushort)pd[1][j]));
                float v2 = gelu_fast(accN[ai][nh][bi][2] + bf2f((ushort)ps[2][j]) + bf2f((ushort)pd[2][j]));
                float v3 = gelu_fast(accN[ai][nh][bi][3] + bf2f((ushort)ps[3][j]) + bf2f((ushort)pd[3][j]));
                float s = v0; int d = dd[0];
                if (dd[1] == d) s += v1; else { fadd_native(&S[(size_t)d * HIDD + col], s); d = dd[1]; s = v1; }
                if (dd[2] == d) s += v2; else { fadd_native(&S[(size_t)d * HIDD + col], s); d = dd[2]; s = v2; }
                if (dd[3] == d) s += v3; else { fadd_native(&S[(size_t)d * HIDD + col], s); d = dd[3]; s = v3; }
                fadd_native(&S[(size_t)d * HIDD + col], s);
            }
    }
}

// ---- node phase 2 + LN ----
__global__ __launch_bounds__(256) void hn_gemm_kernel(
    const float* __restrict__ S, const ushort* __restrict__ WTv2,
    const void* __restrict__ bv2, const u32* __restrict__ cnt,
    const void* __restrict__ h,
    const void* __restrict__ nvg, const void* __restrict__ nvb,
    void* __restrict__ out, const u32* __restrict__ flags)
{
    const bool f32 = flags[0] != 0;
    constexpr int LDV = 260;
    __shared__ float Vsm[64 * LDV];

    const int tid = threadIdx.x;
    const int wid = tid >> 6, lane = tid & 63;
    const int l16 = lane & 15, lg = lane >> 4;
    const int node0 = blockIdx.x * 64;
    const int n0 = wid * 64;

    size_t ra[4];
    #pragma unroll
    for (int ai = 0; ai < 4; ++ai) {
        int row = node0 + ai * 16 + l16;
        ra[ai] = (size_t)(row < NNODE ? row : NNODE - 1) * HIDD;
    }
    int bb[4];
    #pragma unroll
    for (int bi = 0; bi < 4; ++bi) bb[bi] = (n0 + bi * 16 + l16) * HIDD;

    f4 acc[4][4] = {};
    for (int kc = 0; kc < 4; ++kc) {
        #pragma unroll
        for (int ks = 0; ks < 2; ++ks) {
            int kk = kc * 64 + ks * 32 + lg * 8;
            bf8 b[4];
            #pragma unroll
            for (int bi = 0; bi < 4; ++bi) b[bi] = *(const bf8*)&WTv2[bb[bi] + kk];
            #pragma unroll
            for (int ai = 0; ai < 4; ++ai) {
                bf8 a = load8(S, ra[ai] + kk, true);
                #pragma unroll
                for (int bi = 0; bi < 4; ++bi)
                    acc[ai][bi] = __builtin_amdgcn_mfma_f32_16x16x32_bf16(a, b[bi], acc[ai][bi], 0, 0, 0);
            }
        }
    }

    #pragma unroll
    for (int bi = 0; bi < 4; ++bi) {
        int col = n0 + bi * 16 + l16;
        float b2 = loadf(bv2, col, f32);
        #pragma unroll
        for (int ai = 0; ai < 4; ++ai)
            #pragma unroll
            for (int r = 0; r < 4; ++r) {
                int rowl = ai * 16 + lg * 4 + r;
                int gr = node0 + rowl;
                int grc = gr < NNODE ? gr : NNODE - 1;
                float c = (float)cnt[grc];
                float inv = 1.0f / fmaxf(c, 1.0f);
                float val = (acc[ai][bi][r] + c * b2) * inv
                          + loadf(h, (size_t)grc * HIDD + col, f32);
                Vsm[rowl * LDV + col] = val;
            }
    }
    __syncthreads();

    #pragma unroll
    for (int rr = 0; rr < 4; ++rr) {
        int rowl = wid * 16 + lg * 4 + rr;
        int gr = node0 + rowl;
        float x[16];
        #pragma unroll
        for (int f = 0; f < 16; ++f) x[f] = Vsm[rowl * LDV + f * 16 + l16];
        float s = 0.f;
        #pragma unroll
        for (int f = 0; f < 16; ++f) s += x[f];
        s += __shfl_xor(s, 1); s += __shfl_xor(s, 2);
        s += __shfl_xor(s, 4); s += __shfl_xor(s, 8);
        float mu = s * (1.0f / 256.0f);
        float q = 0.f;
        #pragma unroll
        for (int f = 0; f < 16; ++f) { float d = x[f] - mu; q += d * d; }
        q += __shfl_xor(q, 1); q += __shfl_xor(q, 2);
        q += __shfl_xor(q, 4); q += __shfl_xor(q, 8);
        float rstd = rsqrtf(q * (1.0f / 256.0f) + 1e-5f);
        if (gr < NNODE) {
            #pragma unroll
            for (int f = 0; f < 16; ++f) {
                int col = f * 16 + l16;
                float y = (x[f] - mu) * rstd * loadf(nvg, col, f32) + loadf(nvb, col, f32);
                storef(out, (size_t)gr * HIDD + col, y, f32);
            }
        }
    }
}

extern "C" void kernel_launch(void* const* d_in, const int* in_sizes, int n_in,
                              void* d_out, int out_size, void* d_ws, size_t ws_size,
                              hipStream_t stream)
{
    (void)in_sizes; (void)n_in; (void)out_size; (void)ws_size;
    const void* h   = d_in[0];
    const void* e   = d_in[1];
    const int*  ei  = (const int*)d_in[2];
    const void* We1 = d_in[3];
    const void* be1 = d_in[4];
    const void* We2 = d_in[5];
    const void* be2 = d_in[6];
    const void* Wv1 = d_in[7];
    const void* bv1 = d_in[8];
    const void* Wv2 = d_in[9];
    const void* bv2 = d_in[10];
    const void* neg = d_in[11];
    const void* neb = d_in[12];
    const void* nvg = d_in[13];
    const void* nvb = d_in[14];

    char* ws = (char*)d_ws;
    u32*   flags = (u32*)ws;
    float* S     = (float*)(ws + 256);
    u32*   cnt   = (u32*)(ws + 256 + (size_t)NNODE * HIDD * 4);
    size_t off = 256 + (size_t)NNODE * HIDD * 4 + ((size_t)NNODE * 4 + 255) / 256 * 256;
    int*   head = (int*)(ws + off);            off += ((size_t)NNODE * 4 + 255) / 256 * 256;
    int*   perm = (int*)(ws + off);            off += (size_t)NEDGE * 4;
    int*   dsts = (int*)(ws + off);            off += (size_t)NEDGE * 4;
    ushort* WTb  = (ushort*)(ws + off);
    ushort* WTe  = WTb;                        // [256][256]
    ushort* WT1c = WTb + 65536;                // [128][128]
    ushort* WT2  = WTb + 81920;                // [128][128]
    ushort* WTv  = WTb + 98304;                // [512][256]
    ushort* WvcT = WTb + 229376;               // [256][128]
    ushort* WTv2 = WTb + 262144;               // [256][256]
    ushort* hb   = WTb + 327680;                       // [10000][256] bf16
    ushort* Qab  = hb + (size_t)NNODE * HIDD;          // [10000][256] bf16 (permuted)
    ushort* Pab  = Qab + (size_t)NNODE * 256;          // [10000][512] bf16 (permuted)

    hipMemsetAsync(S, 0, (size_t)NNODE * HIDD * 4 + (size_t)NNODE * 4, stream);
    detect_kernel<<<1, 64, 0, stream>>>((const u32*)h, (const u32*)ei, flags);

    prep_kernel<<<1280, 256, 0, stream>>>(We1, We2, Wv1, Wv2, WTb, flags);
    hconv_kernel<<<(NNODE * HIDD / 8 + 255) / 256, 256, 0, stream>>>(h, hb, flags);
    count_kernel<<<(NEDGE + 255) / 256, 256, 0, stream>>>(ei, cnt, flags);
    scan_kernel<<<1, 256, 0, stream>>>(cnt, head);
    fill_kernel<<<(NEDGE + 255) / 256, 256, 0, stream>>>(ei, head, perm, dsts, flags);

    qp2_kernel<<<2 * QPB, 256, 0, stream>>>(hb, WTe, WTv, be1, bv1, Qab, Pab, flags);

    fused_kernel<<<FWG, 512, 0, stream>>>(e, ei, perm, dsts,
                                          WT1c, WT2, be2, Qab,
                                          neg, neb, WvcT, Pab,
                                          S, d_out, flags);
    hn_gemm_kernel<<<(NNODE + 63) / 64, 256, 0, stream>>>(S, WTv2, bv2, cnt, h,
                                                          nvg, nvb, d_out, flags);
}

// Round 15
// 335.261 us; speedup vs baseline: 1.2881x; 1.0789x over previous
//
#include <hip/hip_runtime.h>
#include <hip/hip_bf16.h>

#define NNODE 10000
#define NEDGE 160000
#define HIDD  256
#define ED    128
#define CAT   640

typedef short bf8 __attribute__((ext_vector_type(8)));
typedef short bf4 __attribute__((ext_vector_type(4)));
typedef float f4  __attribute__((ext_vector_type(4)));
typedef unsigned int u32;

__device__ __forceinline__ float bf2f(ushort u) {
    return __uint_as_float(((unsigned)u) << 16);
}
__device__ __forceinline__ ushort f2bf(float f) {
    unsigned u = __float_as_uint(f);
    return (ushort)((u + 0x7fffu + ((u >> 16) & 1u)) >> 16);
}
// fast tanh-form gelu (|err| ~3e-3)
__device__ __forceinline__ float gelu_fast(float x) {
    float x2 = x * x;
    float u = 0.7978845608028654f * x * (1.0f + 0.044715f * x2);
    float au = fabsf(u);
    float ex = __expf(2.0f * au);
    float t = 1.0f - 2.0f / (1.0f + ex);
    t = copysignf(t, u);
    return 0.5f * x * (1.0f + t);
}
__device__ __forceinline__ int clampi(int v) {
    return ((unsigned)v >= (unsigned)NNODE) ? 0 : v;
}
__device__ __forceinline__ int getidx(const int* ei, bool i64, int pos) {
    int v = i64 ? ei[2 * pos] : ei[pos];
    return clampi(v);
}
__device__ __forceinline__ float loadf(const void* p, size_t idx, bool f32) {
    return f32 ? ((const float*)p)[idx] : bf2f(((const ushort*)p)[idx]);
}
__device__ __forceinline__ bf8 load8(const void* p, size_t idx, bool f32) {
    if (f32) {
        const float* fp = (const float*)p + idx;
        f4 lo = *(const f4*)fp, hi = *(const f4*)(fp + 4);
        bf8 r;
        r[0] = (short)f2bf(lo[0]); r[1] = (short)f2bf(lo[1]);
        r[2] = (short)f2bf(lo[2]); r[3] = (short)f2bf(lo[3]);
        r[4] = (short)f2bf(hi[0]); r[5] = (short)f2bf(hi[1]);
        r[6] = (short)f2bf(hi[2]); r[7] = (short)f2bf(hi[3]);
        return r;
    }
    return *(const bf8*)((const ushort*)p + idx);
}
__device__ __forceinline__ void storef(void* p, size_t idx, float v, bool f32) {
    if (f32) ((float*)p)[idx] = v;
    else     ((ushort*)p)[idx] = f2bf(v);
}
__device__ __forceinline__ void fadd_native(float* p, float v) {
    unsafeAtomicAdd(p, v);
}

// ---- runtime dtype detection (wave-parallel) ----
__global__ void detect_kernel(const u32* __restrict__ h_u32,
                              const u32* __restrict__ ei_u32,
                              u32* __restrict__ flags) {
    int t = threadIdx.x;
    u32 e8 = (h_u32[t] >> 7) & 0xFFu;
    bool inw = (e8 >= 100u && e8 <= 150u);
    unsigned long long m = __ballot(inw);
    bool hi_nz = (t < 16) ? (ei_u32[2 * t + 1] != 0u) : false;
    unsigned long long m2 = __ballot(hi_nz);
    if (t == 0) {
        flags[0] = (__popcll(m) < 40) ? 1u : 0u;
        flags[1] = (m2 == 0ull) ? 1u : 0u;
    }
}

// ---- consolidated weight transposes ----
__global__ void prep_kernel(const void* __restrict__ We1, const void* __restrict__ We2,
                            const void* __restrict__ Wv1, const void* __restrict__ Wv2,
                            ushort* __restrict__ WT, const u32* __restrict__ flags) {
    const bool f32 = flags[0] != 0;
    int idx = blockIdx.x * 256 + threadIdx.x;
    if (idx >= 327680) return;
    const void* W; int base, k0, K, Wld;
    if      (idx <  32768) { W = We1; base = 0;      k0 = 0;   K = 256; Wld = 128; }
    else if (idx <  65536) { W = We1; base = 32768;  k0 = 256; K = 256; Wld = 128; }
    else if (idx <  81920) { W = We1; base = 65536;  k0 = 512; K = 128; Wld = 128; }
    else if (idx <  98304) { W = We2; base = 81920;  k0 = 0;   K = 128; Wld = 128; }
    else if (idx < 163840) { W = Wv1; base = 98304;  k0 = 0;   K = 256; Wld = 256; }
    else if (idx < 229376) { W = Wv1; base = 163840; k0 = 256; K = 256; Wld = 256; }
    else if (idx < 262144) { W = Wv1; base = 229376; k0 = 512; K = 128; Wld = 256; }
    else                   { W = Wv2; base = 262144; k0 = 0;   K = 256; Wld = 256; }
    int local = idx - base;
    int k = local & (K - 1);
    int n = local / K;
    WT[idx] = f2bf(loadf(W, (size_t)(k0 + k) * Wld + n, f32));
}

// ---- h convert to bf16 ----
__global__ void hconv_kernel(const void* __restrict__ h, ushort* __restrict__ hb,
                             const u32* __restrict__ flags) {
    const bool f32 = flags[0] != 0;
    int i = blockIdx.x * 256 + threadIdx.x;
    if (i < NNODE * HIDD / 8)
        *(bf8*)&hb[(size_t)i * 8] = load8(h, (size_t)i * 8, f32);
}

// ---- per-dst edge counts ----
__global__ void count_kernel(const int* __restrict__ ei, u32* __restrict__ cnt,
                             const u32* __restrict__ flags) {
    bool i64 = flags[1] != 0;
    int i = blockIdx.x * 256 + threadIdx.x;
    if (i < NEDGE) atomicAdd(&cnt[getidx(ei, i64, NEDGE + i)], 1u);
}

// ---- exclusive prefix scan over cnt -> head ----
__global__ void scan_kernel(const u32* __restrict__ cnt, int* __restrict__ head) {
    __shared__ u32 part[256];
    __shared__ u32 base[256];
    int t = threadIdx.x;
    u32 s = 0;
    for (int j = 0; j < 40; ++j) {
        int i = t * 40 + j;
        if (i < NNODE) s += cnt[i];
    }
    part[t] = s;
    __syncthreads();
    if (t == 0) {
        u32 run = 0;
        for (int i = 0; i < 256; ++i) { base[i] = run; run += part[i]; }
    }
    __syncthreads();
    u32 run = base[t];
    for (int j = 0; j < 40; ++j) {
        int i = t * 40 + j;
        if (i < NNODE) { head[i] = (int)run; run += cnt[i]; }
    }
}

// ---- bucket fill ----
__global__ void fill_kernel(const int* __restrict__ ei, int* __restrict__ head,
                            int* __restrict__ perm, int* __restrict__ dsts,
                            const u32* __restrict__ flags) {
    bool i64 = flags[1] != 0;
    int i = blockIdx.x * 256 + threadIdx.x;
    if (i < NEDGE) {
        int d = getidx(ei, i64, NEDGE + i);
        int pos = atomicAdd(&head[d], 1);
        perm[pos] = i;
        dsts[pos] = d;
    }
}

// ---- node-level projections, permuted layout + bias folding ----
template<int NB>
__device__ __forceinline__ void qp_body(const ushort* __restrict__ hb,
                                        const ushort* __restrict__ WT,
                                        const void* __restrict__ bias,
                                        ushort* __restrict__ O, int bid, bool f32) {
    const int tid = threadIdx.x;
    const int wid = tid >> 6, lane = tid & 63;
    const int l16 = lane & 15, lg = lane >> 4;
    const int node0 = bid * 64;
    const int N = NB * 64;
    const int n0 = wid * (NB * 16);

    size_t ra[4];
    #pragma unroll
    for (int ai = 0; ai < 4; ++ai) {
        int row = node0 + ai * 16 + l16;
        ra[ai] = (size_t)(row < NNODE ? row : NNODE - 1) * HIDD;
    }
    int bb[NB];
    #pragma unroll
    for (int bi = 0; bi < NB; ++bi) bb[bi] = (n0 + bi * 16 + l16) * HIDD;

    f4 acc[4][NB] = {};
    for (int kc = 0; kc < 4; ++kc) {
        #pragma unroll
        for (int ks = 0; ks < 2; ++ks) {
            int kk = kc * 64 + ks * 32 + lg * 8;
            bf8 b[NB];
            #pragma unroll
            for (int bi = 0; bi < NB; ++bi) b[bi] = *(const bf8*)&WT[bb[bi] + kk];
            #pragma unroll
            for (int ai = 0; ai < 4; ++ai) {
                bf8 a = *(const bf8*)&hb[ra[ai] + kk];
                #pragma unroll
                for (int bi = 0; bi < NB; ++bi)
                    acc[ai][bi] = __builtin_amdgcn_mfma_f32_16x16x32_bf16(a, b[bi], acc[ai][bi], 0, 0, 0);
            }
        }
    }
    #pragma unroll
    for (int bi = 0; bi < NB; ++bi) {
        int col = n0 + bi * 16 + l16;
        int pcol; float badd;
        if constexpr (NB == 4) {
            int hh = col >> 7, c = col & 127;
            badd = (hh == 0) ? loadf(bias, c, f32) : 0.f;
            pcol = hh * 128 + (c & 15) * 8 + (c >> 4);
        } else {
            int hh = col >> 8, c = col & 255;
            badd = (hh == 0) ? loadf(bias, c, f32) : 0.f;
            int nh2 = c >> 7, rem = c & 127, w = rem >> 5, b2 = (rem >> 4) & 1, l = c & 15;
            pcol = hh * 256 + w * 64 + l * 4 + nh2 * 2 + b2;
        }
        #pragma unroll
        for (int ai = 0; ai < 4; ++ai)
            #pragma unroll
            for (int r = 0; r < 4; ++r) {
                int gr = node0 + ai * 16 + lg * 4 + r;
                if (gr < NNODE) O[(size_t)gr * N + pcol] = f2bf(acc[ai][bi][r] + badd);
            }
    }
}

#define QPB ((NNODE + 63) / 64)
__global__ __launch_bounds__(256) void qp2_kernel(
    const ushort* __restrict__ hb, const ushort* __restrict__ WTe,
    const ushort* __restrict__ WTv, const void* __restrict__ be1,
    const void* __restrict__ bv1, ushort* __restrict__ Qab,
    ushort* __restrict__ Pab, const u32* __restrict__ flags) {
    const bool f32 = flags[0] != 0;
    if (blockIdx.x < QPB) qp_body<4>(hb, WTe, be1, Qab, blockIdx.x, f32);
    else                  qp_body<8>(hb, WTv, bv1, Pab, blockIdx.x - QPB, f32);
}

// ============ FUSED edge+node1 (dst-sorted), 64 edges/block, 256 thr ============
// Full-width LDS staging; residual + e_new output served from LDS.
#define FWG (NEDGE / 64)   // 2500 blocks
__global__ __launch_bounds__(256) void fused_kernel(
    const void* __restrict__ e, const int* __restrict__ ei,
    const int* __restrict__ perm, const int* __restrict__ dsts,
    const ushort* __restrict__ WT1c,
    const ushort* __restrict__ WT2, const void* __restrict__ be2,
    const ushort* __restrict__ Qab,
    const void* __restrict__ neg, const void* __restrict__ neb,
    const ushort* __restrict__ WvcT,
    const ushort* __restrict__ Pab,
    float* __restrict__ S, void* __restrict__ out,
    const u32* __restrict__ flags)
{
    const bool f32 = flags[0] != 0, i64 = flags[1] != 0;
    __shared__ ushort Asm[64 * 136];    // 17408 B : e rows (bf16, full 128 wide)
    __shared__ ushort Bsm[128 * 136];   // 34816 B : weight tile (full K=128)
    __shared__ ushort Tsm[64 * 136];    // 17408 B : T1, then e_new bf16
    __shared__ int PermS[64], SrcS[64], DstS[64];   // 768 B -> 70400 B total

    // bijective XCD swizzle (nwg=2500: q=312, r=4)
    int orig = blockIdx.x;
    int xcd = orig & 7, slot = orig >> 3;
    int bid = (xcd < 4 ? xcd * 313 : 4 * 313 + (xcd - 4) * 312) + slot;

    const int tid = threadIdx.x;
    const int wid = tid >> 6, lane = tid & 63;
    const int l16 = lane & 15, lg = lane >> 4;
    const int edge0 = bid * 64;
    const int rm = wid * 16;

    if (tid < 64) {
        int eid = perm[edge0 + tid];
        PermS[tid] = eid;
        SrcS[tid] = getidx(ei, i64, eid);
        DstS[tid] = dsts[edge0 + tid];
    }
    __syncthreads();

    // ---- stage A (e rows, full width, once) + B for phase 1 ----
    #pragma unroll
    for (int j = 0; j < 4; ++j) {
        int s2 = tid + j * 256;              // 1024 chunks of 8 elems
        int r = s2 >> 4, c8 = (s2 & 15) * 8;
        *(bf8*)&Asm[r * 136 + c8] = load8(e, (size_t)PermS[r] * ED + c8, f32);
    }
    #pragma unroll
    for (int it = 0; it < 8; ++it) {
        int s2 = tid + it * 256;             // 2048 chunks
        int n = s2 >> 4, c8 = (s2 & 15) * 8;
        *(bf8*)&Bsm[n * 136 + c8] = *(const bf8*)&WT1c[n * 128 + c8];
    }
    __syncthreads();

    // ---------- phase 1: T1 = e @ WT1c^T (K=128) ----------
    f4 acc[8] = {};
    #pragma unroll
    for (int kc = 0; kc < 2; ++kc)
        #pragma unroll
        for (int ks = 0; ks < 2; ++ks) {
            int ko = kc * 64 + ks * 32 + lg * 8;
            bf8 a = *(const bf8*)&Asm[(rm + l16) * 136 + ko];
            #pragma unroll
            for (int f = 0; f < 8; ++f) {
                bf8 b = *(const bf8*)&Bsm[(f * 16 + l16) * 136 + ko];
                acc[f] = __builtin_amdgcn_mfma_f32_16x16x32_bf16(a, b, acc[f], 0, 0, 0);
            }
        }

    // epilogue 1: + (be1 in Qab) + Qa[src] + Qb[dst], gelu -> Tsm (wave-private rows)
    {
        bf8 qs[4], qd[4];
        #pragma unroll
        for (int r = 0; r < 4; ++r) {
            int row = rm + lg * 4 + r;
            qs[r] = *(const bf8*)&Qab[(size_t)SrcS[row] * 256 + l16 * 8];
            qd[r] = *(const bf8*)&Qab[(size_t)DstS[row] * 256 + 128 + l16 * 8];
        }
        #pragma unroll
        for (int f = 0; f < 8; ++f)
            #pragma unroll
            for (int r = 0; r < 4; ++r) {
                float val = acc[f][r] + bf2f((ushort)qs[r][f]) + bf2f((ushort)qd[r][f]);
                Tsm[(rm + lg * 4 + r) * 136 + f * 16 + l16] = f2bf(gelu_fast(val));
            }
    }
    __syncthreads();   // protect Bsm overwrite (P1 b-reads done)

    // ---- stage B for phase 2 ----
    #pragma unroll
    for (int it = 0; it < 8; ++it) {
        int s2 = tid + it * 256;
        int n = s2 >> 4, c8 = (s2 & 15) * 8;
        *(bf8*)&Bsm[n * 136 + c8] = *(const bf8*)&WT2[n * 128 + c8];
    }
    __syncthreads();

    // ---------- phase 2: T2 = T1 @ WT2^T (K=128) ----------
    f4 acc2[8] = {};
    #pragma unroll
    for (int kc = 0; kc < 2; ++kc)
        #pragma unroll
        for (int ks = 0; ks < 2; ++ks) {
            int ko = kc * 64 + ks * 32 + lg * 8;
            bf8 a = *(const bf8*)&Tsm[(rm + l16) * 136 + ko];   // wave-private rows
            #pragma unroll
            for (int f = 0; f < 8; ++f) {
                bf8 b = *(const bf8*)&Bsm[(f * 16 + l16) * 136 + ko];
                acc2[f] = __builtin_amdgcn_mfma_f32_16x16x32_bf16(a, b, acc2[f], 0, 0, 0);
            }
        }

    // epilogue 2: + be2 + e residual (from Asm), LN -> Tsm (bf16 e_new)
    {
        float v[8][4];
        #pragma unroll
        for (int f = 0; f < 8; ++f) {
            int col = f * 16 + l16;
            float bias = loadf(be2, col, f32);
            #pragma unroll
            for (int r = 0; r < 4; ++r) {
                int row = rm + lg * 4 + r;
                v[f][r] = acc2[f][r] + bias + bf2f(Asm[row * 136 + col]);
            }
        }
        #pragma unroll
        for (int r = 0; r < 4; ++r) {
            float s = 0.f;
            #pragma unroll
            for (int f = 0; f < 8; ++f) s += v[f][r];
            s += __shfl_xor(s, 1); s += __shfl_xor(s, 2);
            s += __shfl_xor(s, 4); s += __shfl_xor(s, 8);
            float mu = s * (1.0f / 128.0f);
            float q = 0.f;
            #pragma unroll
            for (int f = 0; f < 8; ++f) { float d = v[f][r] - mu; q += d * d; }
            q += __shfl_xor(q, 1); q += __shfl_xor(q, 2);
            q += __shfl_xor(q, 4); q += __shfl_xor(q, 8);
            float rstd = rsqrtf(q * (1.0f / 128.0f) + 1e-5f);
            int row = rm + lg * 4 + r;
            #pragma unroll
            for (int f = 0; f < 8; ++f) {
                int col = f * 16 + l16;
                float y = (v[f][r] - mu) * rstd * loadf(neg, col, f32) + loadf(neb, col, f32);
                Tsm[row * 136 + col] = f2bf(y);
            }
        }
    }
    __syncthreads();   // publish e_new (Tsm) cross-wave; Bsm free

    // ---- bulk e_new global write from Tsm (coalesced, vector) ----
    {
        int row = tid >> 2, pc = (tid & 3) * 32;
        size_t obase = (size_t)NNODE * HIDD + (size_t)PermS[row] * ED + pc;
        #pragma unroll
        for (int q2 = 0; q2 < 4; ++q2) {
            bf8 w = *(const bf8*)&Tsm[row * 136 + pc + q2 * 8];
            if (f32) {
                f4 lo, hi;
                lo[0] = bf2f((ushort)w[0]); lo[1] = bf2f((ushort)w[1]);
                lo[2] = bf2f((ushort)w[2]); lo[3] = bf2f((ushort)w[3]);
                hi[0] = bf2f((ushort)w[4]); hi[1] = bf2f((ushort)w[5]);
                hi[2] = bf2f((ushort)w[6]); hi[3] = bf2f((ushort)w[7]);
                *(f4*)((float*)out + obase + q2 * 8) = lo;
                *(f4*)((float*)out + obase + q2 * 8 + 4) = hi;
            } else {
                *(bf8*)((ushort*)out + obase + q2 * 8) = w;
            }
        }
    }

    // ---------- phase 3: U = e_new @ WvcT^T (K=128, N=256 in 2 halves) ----------
    f4 accN[4][2][2] = {};   // [ai][nh][bi]
    #pragma unroll
    for (int nh = 0; nh < 2; ++nh) {
        #pragma unroll
        for (int it = 0; it < 8; ++it) {
            int s2 = tid + it * 256;
            int n = s2 >> 4, c8 = (s2 & 15) * 8;
            *(bf8*)&Bsm[n * 136 + c8] = *(const bf8*)&WvcT[(nh * 128 + n) * 128 + c8];
        }
        __syncthreads();
        #pragma unroll
        for (int kc = 0; kc < 2; ++kc)
            #pragma unroll
            for (int ks = 0; ks < 2; ++ks) {
                int ko = kc * 64 + ks * 32 + lg * 8;
                bf8 a[4], b[2];
                #pragma unroll
                for (int ai = 0; ai < 4; ++ai)
                    a[ai] = *(const bf8*)&Tsm[(ai * 16 + l16) * 136 + ko];
                #pragma unroll
                for (int bi = 0; bi < 2; ++bi)
                    b[bi] = *(const bf8*)&Bsm[(wid * 32 + bi * 16 + l16) * 136 + ko];
                #pragma unroll
                for (int ai = 0; ai < 4; ++ai)
                    #pragma unroll
                    for (int bi = 0; bi < 2; ++bi)
                        accN[ai][nh][bi] = __builtin_amdgcn_mfma_f32_16x16x32_bf16(a[ai], b[bi], accN[ai][nh][bi], 0, 0, 0);
            }
        __syncthreads();   // before next nh overwrites Bsm
    }

    // epilogue 3: + (bv1 in Pab) + Pa[src] + Pb[dst], gelu, merged scatter
    #pragma unroll
    for (int ai = 0; ai < 4; ++ai) {
        int p0 = ai * 16 + lg * 4;
        int dd[4], ss[4];
        #pragma unroll
        for (int r = 0; r < 4; ++r) { dd[r] = DstS[p0 + r]; ss[r] = SrcS[p0 + r]; }
        bf4 ps[4], pd[4];
        #pragma unroll
        for (int r = 0; r < 4; ++r) {
            ps[r] = *(const bf4*)&Pab[(size_t)ss[r] * 512 + wid * 64 + l16 * 4];
            pd[r] = *(const bf4*)&Pab[(size_t)dd[r] * 512 + 256 + wid * 64 + l16 * 4];
        }
        #pragma unroll
        for (int nh = 0; nh < 2; ++nh)
            #pragma unroll
            for (int bi = 0; bi < 2; ++bi) {
                int col = nh * 128 + wid * 32 + bi * 16 + l16;
                const int j = nh * 2 + bi;
                float v0 = gelu_fast(accN[0 + ai - ai][nh][bi][0] * 0.f + accN[ai][nh][bi][0] + bf2f((ushort)ps[0][j]) + bf2f((ushort)pd[0][j]));
                float v1 = gelu_fast(accN[ai][nh][bi][1] + bf2f((ushort)ps[1][j]) + bf2f((ushort)pd[1][j]));
                float v2 = gelu_fast(accN[ai][nh][bi][2] + bf2f((ushort)ps[2][j]) + bf2f((ushort)pd[2][j]));
                float v3 = gelu_fast(accN[ai][nh][bi][3] + bf2f((ushort)ps[3][j]) + bf2f((ushort)pd[3][j]));
                float s = v0; int d = dd[0];
                if (dd[1] == d) s += v1; else { fadd_native(&S[(size_t)d * HIDD + col], s); d = dd[1]; s = v1; }
                if (dd[2] == d) s += v2; else { fadd_native(&S[(size_t)d * HIDD + col], s); d = dd[2]; s = v2; }
                if (dd[3] == d) s += v3; else { fadd_native(&S[(size_t)d * HIDD + col], s); d = dd[3]; s = v3; }
                fadd_native(&S[(size_t)d * HIDD + col], s);
            }
    }
}

// ---- node phase 2 + LN ----
__global__ __launch_bounds__(256) void hn_gemm_kernel(
    const float* __restrict__ S, const ushort* __restrict__ WTv2,
    const void* __restrict__ bv2, const u32* __restrict__ cnt,
    const void* __restrict__ h,
    const void* __restrict__ nvg, const void* __restrict__ nvb,
    void* __restrict__ out, const u32* __restrict__ flags)
{
    const bool f32 = flags[0] != 0;
    constexpr int LDV = 260;
    __shared__ float Vsm[64 * LDV];

    const int tid = threadIdx.x;
    const int wid = tid >> 6, lane = tid & 63;
    const int l16 = lane & 15, lg = lane >> 4;
    const int node0 = blockIdx.x * 64;
    const int n0 = wid * 64;

    size_t ra[4];
    #pragma unroll
    for (int ai = 0; ai < 4; ++ai) {
        int row = node0 + ai * 16 + l16;
        ra[ai] = (size_t)(row < NNODE ? row : NNODE - 1) * HIDD;
    }
    int bb[4];
    #pragma unroll
    for (int bi = 0; bi < 4; ++bi) bb[bi] = (n0 + bi * 16 + l16) * HIDD;

    f4 acc[4][4] = {};
    for (int kc = 0; kc < 4; ++kc) {
        #pragma unroll
        for (int ks = 0; ks < 2; ++ks) {
            int kk = kc * 64 + ks * 32 + lg * 8;
            bf8 b[4];
            #pragma unroll
            for (int bi = 0; bi < 4; ++bi) b[bi] = *(const bf8*)&WTv2[bb[bi] + kk];
            #pragma unroll
            for (int ai = 0; ai < 4; ++ai) {
                bf8 a = load8(S, ra[ai] + kk, true);
                #pragma unroll
                for (int bi = 0; bi < 4; ++bi)
                    acc[ai][bi] = __builtin_amdgcn_mfma_f32_16x16x32_bf16(a, b[bi], acc[ai][bi], 0, 0, 0);
            }
        }
    }

    #pragma unroll
    for (int bi = 0; bi < 4; ++bi) {
        int col = n0 + bi * 16 + l16;
        float b2 = loadf(bv2, col, f32);
        #pragma unroll
        for (int ai = 0; ai < 4; ++ai)
            #pragma unroll
            for (int r = 0; r < 4; ++r) {
                int rowl = ai * 16 + lg * 4 + r;
                int gr = node0 + rowl;
                int grc = gr < NNODE ? gr : NNODE - 1;
                float c = (float)cnt[grc];
                float inv = 1.0f / fmaxf(c, 1.0f);
                float val = (acc[ai][bi][r] + c * b2) * inv
                          + loadf(h, (size_t)grc * HIDD + col, f32);
                Vsm[rowl * LDV + col] = val;
            }
    }
    __syncthreads();

    #pragma unroll
    for (int rr = 0; rr < 4; ++rr) {
        int rowl = wid * 16 + lg * 4 + rr;
        int gr = node0 + rowl;
        float x[16];
        #pragma unroll
        for (int f = 0; f < 16; ++f) x[f] = Vsm[rowl * LDV + f * 16 + l16];
        float s = 0.f;
        #pragma unroll
        for (int f = 0; f < 16; ++f) s += x[f];
        s += __shfl_xor(s, 1); s += __shfl_xor(s, 2);
        s += __shfl_xor(s, 4); s += __shfl_xor(s, 8);
        float mu = s * (1.0f / 256.0f);
        float q = 0.f;
        #pragma unroll
        for (int f = 0; f < 16; ++f) { float d = x[f] - mu; q += d * d; }
        q += __shfl_xor(q, 1); q += __shfl_xor(q, 2);
        q += __shfl_xor(q, 4); q += __shfl_xor(q, 8);
        float rstd = rsqrtf(q * (1.0f / 256.0f) + 1e-5f);
        if (gr < NNODE) {
            #pragma unroll
            for (int f = 0; f < 16; ++f) {
                int col = f * 16 + l16;
                float y = (x[f] - mu) * rstd * loadf(nvg, col, f32) + loadf(nvb, col, f32);
                storef(out, (size_t)gr * HIDD + col, y, f32);
            }
        }
    }
}

extern "C" void kernel_launch(void* const* d_in, const int* in_sizes, int n_in,
                              void* d_out, int out_size, void* d_ws, size_t ws_size,
                              hipStream_t stream)
{
    (void)in_sizes; (void)n_in; (void)out_size; (void)ws_size;
    const void* h   = d_in[0];
    const void* e   = d_in[1];
    const int*  ei  = (const int*)d_in[2];
    const void* We1 = d_in[3];
    const void* be1 = d_in[4];
    const void* We2 = d_in[5];
    const void* be2 = d_in[6];
    const void* Wv1 = d_in[7];
    const void* bv1 = d_in[8];
    const void* Wv2 = d_in[9];
    const void* bv2 = d_in[10];
    const void* neg = d_in[11];
    const void* neb = d_in[12];
    const void* nvg = d_in[13];
    const void* nvb = d_in[14];

    char* ws = (char*)d_ws;
    u32*   flags = (u32*)ws;
    float* S     = (float*)(ws + 256);
    u32*   cnt   = (u32*)(ws + 256 + (size_t)NNODE * HIDD * 4);
    size_t off = 256 + (size_t)NNODE * HIDD * 4 + ((size_t)NNODE * 4 + 255) / 256 * 256;
    int*   head = (int*)(ws + off);            off += ((size_t)NNODE * 4 + 255) / 256 * 256;
    int*   perm = (int*)(ws + off);            off += (size_t)NEDGE * 4;
    int*   dsts = (int*)(ws + off);            off += (size_t)NEDGE * 4;
    ushort* WTb  = (ushort*)(ws + off);
    ushort* WTe  = WTb;                        // [256][256]
    ushort* WT1c = WTb + 65536;                // [128][128]
    ushort* WT2  = WTb + 81920;                // [128][128]
    ushort* WTv  = WTb + 98304;                // [512][256]
    ushort* WvcT = WTb + 229376;               // [256][128]
    ushort* WTv2 = WTb + 262144;               // [256][256]
    ushort* hb   = WTb + 327680;                       // [10000][256] bf16
    ushort* Qab  = hb + (size_t)NNODE * HIDD;          // [10000][256] bf16 (permuted)
    ushort* Pab  = Qab + (size_t)NNODE * 256;          // [10000][512] bf16 (permuted)

    hipMemsetAsync(S, 0, (size_t)NNODE * HIDD * 4 + (size_t)NNODE * 4, stream);
    detect_kernel<<<1, 64, 0, stream>>>((const u32*)h, (const u32*)ei, flags);

    prep_kernel<<<1280, 256, 0, stream>>>(We1, We2, Wv1, Wv2, WTb, flags);
    hconv_kernel<<<(NNODE * HIDD / 8 + 255) / 256, 256, 0, stream>>>(h, hb, flags);
    count_kernel<<<(NEDGE + 255) / 256, 256, 0, stream>>>(ei, cnt, flags);
    scan_kernel<<<1, 256, 0, stream>>>(cnt, head);
    fill_kernel<<<(NEDGE + 255) / 256, 256, 0, stream>>>(ei, head, perm, dsts, flags);

    qp2_kernel<<<2 * QPB, 256, 0, stream>>>(hb, WTe, WTv, be1, bv1, Qab, Pab, flags);

    fused_kernel<<<FWG, 256, 0, stream>>>(e, ei, perm, dsts,
                                          WT1c, WT2, be2, Qab,
                                          neg, neb, WvcT, Pab,
                                          S, d_out, flags);
    hn_gemm_kernel<<<(NNODE + 63) / 64, 256, 0, stream>>>(S, WTv2, bv2, cnt, h,
                                                          nvg, nvb, d_out, flags);
}